// Round 10
// baseline (331.954 us; speedup 1.0000x reference)
//
#include <hip/hip_runtime.h>
#include <stdint.h>

// Problem constants (fixed by setup_inputs)
constexpr int B   = 2;
constexpr int T   = 2048;
constexpr int D   = 2048;
constexpr int H   = 32;
constexpr int KVH = 8;
constexpr int HD  = 64;          // head dim
constexpr int R   = B * T;       // 4096 rows
constexpr int OKV = KVH * HD;    // 512

using bf16x8 = __attribute__((ext_vector_type(8))) __bf16;
using f32x4  = __attribute__((ext_vector_type(4))) float;
using i32x4  = __attribute__((ext_vector_type(4))) int;

__device__ inline float fast_exp2(float x) {
#if __has_builtin(__builtin_amdgcn_exp2f)
    return __builtin_amdgcn_exp2f(x);    // v_exp_f32: computes 2^x
#else
    return exp2f(x);
#endif
}

__device__ inline float max3f(float a, float b, float c) {
    return fmaxf(fmaxf(a, b), c);        // clang fuses to v_max3_f32 on gfx9+
}

__device__ inline uint16_t f2bf(float f) {
    uint32_t u = __float_as_uint(f);
    u += 0x7fff + ((u >> 16) & 1);   // RNE
    return (uint16_t)(u >> 16);
}

__device__ inline uint32_t pack_bf16(float a, float b) {
#if __has_builtin(__builtin_amdgcn_cvt_pk_bf16_f32)
    union { __attribute__((ext_vector_type(2))) __bf16 v; uint32_t u; } r;
    r.v = __builtin_amdgcn_cvt_pk_bf16_f32(a, b);
    return r.u;
#else
    return (uint32_t)f2bf(a) | ((uint32_t)f2bf(b) << 16);
#endif
}

// async global->LDS, 16B per lane; LDS dest = (wave-uniform) base + lane*16
__device__ inline void async16(const void* g, void* l) {
    __builtin_amdgcn_global_load_lds((const __attribute__((address_space(1))) unsigned int*)g,
                                     (__attribute__((address_space(3))) unsigned int*)l,
                                     16, 0, 0);
}

// ---------------- weight scales: mean(|w|), all 4 weights in one launch --------
__global__ void absmean4_kernel(const float* __restrict__ w0, const float* __restrict__ w1,
                                const float* __restrict__ w2, const float* __restrict__ w3,
                                double* __restrict__ sums) {
    __shared__ float red[256];
    const float* ws[4] = {w0, w1, w2, w3};
    const int ns[4] = {D * D, OKV * D, OKV * D, D * D};
    int wi = blockIdx.y;
    const float* w = ws[wi];
    int n = ns[wi];
    int tid = threadIdx.x;
    float s = 0.f;
    for (int i = blockIdx.x * 256 + tid; i < n; i += gridDim.x * 256)
        s += fabsf(w[i]);
    red[tid] = s;
    __syncthreads();
    for (int st = 128; st > 0; st >>= 1) {
        if (tid < st) red[tid] += red[tid + st];
        __syncthreads();
    }
    if (tid == 0) atomicAdd(&sums[wi], (double)red[0]);
}

// ---------------- ternary weight quantization, all 4 in one launch ----------------
__global__ void quantw4_kernel(const float* __restrict__ w0, const float* __restrict__ w1,
                               const float* __restrict__ w2, const float* __restrict__ w3,
                               int8_t* __restrict__ o0, int8_t* __restrict__ o1,
                               int8_t* __restrict__ o2, int8_t* __restrict__ o3,
                               const double* __restrict__ sums) {
    const float* ws[4] = {w0, w1, w2, w3};
    int8_t* os[4] = {o0, o1, o2, o3};
    const int ns[4] = {D * D, OKV * D, OKV * D, D * D};
    int wi = blockIdx.y;
    const float* w = ws[wi];
    int8_t* o = os[wi];
    int n = ns[wi];
    float wsc = fmaxf((float)(sums[wi] / (double)n), 1e-5f);
    for (int i = blockIdx.x * 256 + threadIdx.x; i < n; i += gridDim.x * 256) {
        float q = rintf(w[i] / wsc);
        q = fminf(fmaxf(q, -1.f), 1.f);
        o[i] = (int8_t)q;
    }
}

// ---------------- fused rmsnorm + absmax int8 quant for q,k,v ----------------
__global__ __launch_bounds__(256) void rmsq3_kernel(const float* __restrict__ X,
        const float* __restrict__ g0, const float* __restrict__ g1, const float* __restrict__ g2,
        int8_t* __restrict__ o0, int8_t* __restrict__ o1, int8_t* __restrict__ o2,
        float* __restrict__ s0, float* __restrict__ s1, float* __restrict__ s2) {
    __shared__ float red[256];
    int row = blockIdx.x, tid = threadIdx.x;
    const float* xr = X + (size_t)row * D;
    float xv[8];
    float ss = 0.f;
#pragma unroll
    for (int i = 0; i < 8; i++) { xv[i] = xr[tid + 256 * i]; ss += xv[i] * xv[i]; }
    red[tid] = ss;
    __syncthreads();
    for (int st = 128; st > 0; st >>= 1) {
        if (tid < st) red[tid] += red[tid + st];
        __syncthreads();
    }
    float rstd = 1.0f / sqrtf(red[0] / (float)D + 1e-6f);

    const float* gs[3] = {g0, g1, g2};
    int8_t* os[3] = {o0, o1, o2};
    float* sc[3] = {s0, s1, s2};
#pragma unroll
    for (int v = 0; v < 3; v++) {
        float xn[8];
        float amax = 0.f;
#pragma unroll
        for (int i = 0; i < 8; i++) {
            xn[i] = xv[i] * rstd * gs[v][tid + 256 * i];
            amax = fmaxf(amax, fabsf(xn[i]));
        }
        __syncthreads();
        red[tid] = amax;
        __syncthreads();
        for (int st = 128; st > 0; st >>= 1) {
            if (tid < st) red[tid] = fmaxf(red[tid], red[tid + st]);
            __syncthreads();
        }
        float xsv = fmaxf(red[0], 1e-5f);
        float q127 = 127.0f / xsv;
#pragma unroll
        for (int i = 0; i < 8; i++) {
            float q = rintf(xn[i] * q127);
            q = fminf(fmaxf(q, -128.f), 127.f);
            os[v][(size_t)row * D + tid + 256 * i] = (int8_t)q;
        }
        if (tid == 0) sc[v][row] = xsv;
    }
}

// ---------------- rmsnorm + quant (single, for o-proj input) ----------------
// register-cached: one global read of the row, like rmsq3
__global__ __launch_bounds__(256) void rmsq_kernel(const float* __restrict__ X,
                                                   const float* __restrict__ g,
                                                   int8_t* __restrict__ Xq,
                                                   float* __restrict__ xs_out) {
    __shared__ float red[256];
    int row = blockIdx.x, tid = threadIdx.x;
    const float* xr = X + (size_t)row * D;
    float xv[8];
    float ss = 0.f;
#pragma unroll
    for (int i = 0; i < 8; i++) { xv[i] = xr[tid + 256 * i]; ss += xv[i] * xv[i]; }
    red[tid] = ss;
    __syncthreads();
    for (int st = 128; st > 0; st >>= 1) {
        if (tid < st) red[tid] += red[tid + st];
        __syncthreads();
    }
    float rstd = 1.0f / sqrtf(red[0] / (float)D + 1e-6f);

    float xn[8];
    float amax = 0.f;
#pragma unroll
    for (int i = 0; i < 8; i++) {
        xn[i] = xv[i] * rstd * g[tid + 256 * i];
        amax = fmaxf(amax, fabsf(xn[i]));
    }
    __syncthreads();
    red[tid] = amax;
    __syncthreads();
    for (int st = 128; st > 0; st >>= 1) {
        if (tid < st) red[tid] = fmaxf(red[tid], red[tid + st]);
        __syncthreads();
    }
    float xs = fmaxf(red[0], 1e-5f);
    float q127 = 127.0f / xs;
#pragma unroll
    for (int i = 0; i < 8; i++) {
        float q = rintf(xn[i] * q127);
        q = fminf(fmaxf(q, -128.f), 127.f);
        Xq[(size_t)row * D + tid + 256 * i] = (int8_t)q;
    }
    if (tid == 0) xs_out[row] = xs;
}

// ===================== unified i8 MFMA GEMM core =====================
// 8 waves as 4 row-groups x 2 col-groups; wave owns 32 rows x 64 cols
// (mt=2 x nt=4). Fragments/output-tile = 6/8 = 0.75 (was 9/8 in r9's
// 1x8 layout): LDS traffic 96 KB per 128x128 K-step, balanced vs MFMA.
// Double-buffered staging, one barrier per K-step.

// ---------------- fused q+k+v projection GEMM ----------------
// grid (24, R/128): x<16 -> q (cols x*128, RoPE bf16 out, stride D);
// x 16..19 -> v (cols (x-16)*128, transposed bf16 out);
// x 20..23 -> k (cols (x-20)*128, RoPE bf16 out, stride OKV).
// One launch instead of three: 768 blocks (3/CU queued) and 2 fewer gaps.
__global__ __launch_bounds__(512, 4) void gemm_qkv(const int8_t* __restrict__ Xqq,
                                                   const int8_t* __restrict__ Xqk,
                                                   const int8_t* __restrict__ Xqv,
                                                   const int8_t* __restrict__ Wq8,
                                                   const int8_t* __restrict__ Wk8,
                                                   const int8_t* __restrict__ Wv8,
                                                   uint16_t* __restrict__ qout,
                                                   uint16_t* __restrict__ kout,
                                                   uint16_t* __restrict__ vt,
                                                   const float* __restrict__ xs,
                                                   const double* __restrict__ wsum,
                                                   const float* __restrict__ cs,
                                                   const float* __restrict__ sn) {
    __shared__ __align__(16) uint8_t As[2][128 * 128];
    __shared__ __align__(16) uint8_t Bs[2][128 * 128];

    const int bx = blockIdx.x;
    const int z  = (bx < 16) ? 0 : ((bx < 20) ? 1 : 2);   // 0=q 1=v 2=k
    const int xb = (bx < 16) ? bx : ((bx - 16) & 3);
    const int8_t* X  = (z == 0) ? Xqq : ((z == 1) ? Xqv : Xqk);
    const int8_t* W  = (z == 0) ? Wq8 : ((z == 1) ? Wv8 : Wk8);
    const float* xsr = (z == 0) ? xs : ((z == 1) ? xs + 2 * R : xs + R);
    const int wi = (z == 0) ? 0 : ((z == 1) ? 2 : 1);
    const double nw = (z == 0) ? (double)(D * D) : (double)(OKV * D);

    const int tid  = threadIdx.x;
    const int lane = tid & 63;
    const int wv   = tid >> 6;
    const int rg   = wv >> 1, cg = wv & 1;       // 4 row-groups x 2 col-groups
    const int n    = lane & 15, quad = lane >> 4;
    const int row0 = blockIdx.y * 128;
    const int col0 = xb * 128;

    i32x4 acc[2][4] = {};

    auto stage = [&](int k0, int buf) {
#pragma unroll
        for (int ps = 0; ps < 2; ps++) {
            int p = ps * 512 + wv * 64 + lane;
            int r = p >> 3, s = p & 7;
            int c = s ^ (r & 7);
            async16(X + (size_t)(row0 + r) * D + k0 + c * 16,
                    &As[buf][(ps * 512 + wv * 64) * 16]);
        }
#pragma unroll
        for (int ps = 0; ps < 2; ps++) {
            int p = ps * 512 + wv * 64 + lane;
            int r = p >> 3, s = p & 7;
            int c = s ^ (r & 7);
            async16(W + (size_t)(col0 + r) * D + k0 + c * 16,
                    &Bs[buf][(ps * 512 + wv * 64) * 16]);
        }
    };

    stage(0, 0);
    __syncthreads();

    for (int k0 = 0; k0 < D; k0 += 128) {
        const int cur = (k0 >> 7) & 1;
        if (k0 + 128 < D) stage(k0 + 128, cur ^ 1);
#pragma unroll
        for (int t = 0; t < 2; t++) {
            i32x4 af[2], bfr[4];
#pragma unroll
            for (int mt = 0; mt < 2; mt++) {
                int r = rg * 32 + mt * 16 + n;
                af[mt] = *(const i32x4*)&As[cur][r * 128 + (((t * 4 + quad) ^ (r & 7)) * 16)];
            }
#pragma unroll
            for (int nt = 0; nt < 4; nt++) {
                int rb = cg * 64 + nt * 16 + n;
                bfr[nt] = *(const i32x4*)&Bs[cur][rb * 128 + (((t * 4 + quad) ^ (rb & 7)) * 16)];
            }
#pragma unroll
            for (int mt = 0; mt < 2; mt++)
#pragma unroll
                for (int nt = 0; nt < 4; nt++)
                    acc[mt][nt] = __builtin_amdgcn_mfma_i32_16x16x64_i8(af[mt], bfr[nt], acc[mt][nt], 0, 0, 0);
        }
        __syncthreads();   // drains prefetch + guards buf reuse
    }

    float w = fmaxf((float)(wsum[wi] / nw), 1e-5f);
    if (z == 1) {
        // v: transposed bf16 write vt[(b*KVH+kvh)*64+d][t]
#pragma unroll
        for (int mt = 0; mt < 2; mt++) {
            int rowb = row0 + rg * 32 + mt * 16 + quad * 4;
            int bb = rowb >> 11;              // rowb / T
            int tb = rowb & (T - 1);
            float fr[4];
#pragma unroll
            for (int r2 = 0; r2 < 4; r2++)
                fr[r2] = w * xsr[rowb + r2] * (1.0f / 127.0f);
#pragma unroll
            for (int nt = 0; nt < 4; nt++) {
                int col = col0 + cg * 64 + nt * 16 + n;
                int kvh = col >> 6, d = col & 63;
                uint2 w2;
                w2.x = pack_bf16((float)acc[mt][nt][0] * fr[0], (float)acc[mt][nt][1] * fr[1]);
                w2.y = pack_bf16((float)acc[mt][nt][2] * fr[2], (float)acc[mt][nt][3] * fr[3]);
                *(uint2*)(vt + ((size_t)(bb * KVH + kvh) * 64 + d) * T + tb) = w2;
            }
        }
    } else {
        uint16_t* out = (z == 0) ? qout : kout;
        const int O   = (z == 0) ? D : OKV;
#pragma unroll
        for (int mt = 0; mt < 2; mt++) {
#pragma unroll
            for (int r2 = 0; r2 < 4; r2++) {
                int row = row0 + rg * 32 + mt * 16 + quad * 4 + r2;
                float f = w * xsr[row] * (1.0f / 127.0f);
                int t = row & (T - 1);
#pragma unroll
                for (int nt = 0; nt < 2; nt++) {      // rope pair (nt, nt+2)
                    int i = nt * 16 + n;              // within-head col < 32
                    float a  = (float)acc[mt][nt][r2] * f;
                    float bb = (float)acc[mt][nt + 2][r2] * f;
                    float c0 = cs[t * HD + i],      s0 = sn[t * HD + i];
                    float c1 = cs[t * HD + i + 32], s1 = sn[t * HD + i + 32];
                    out[(size_t)row * O + col0 + cg * 64 + i]      = f2bf(a * c0 - bb * s0);
                    out[(size_t)row * O + col0 + cg * 64 + i + 32] = f2bf(bb * c1 + a * s1);
                }
            }
        }
    }
}

// ---------------- o-projection GEMM (f32 out) ----------------
__global__ __launch_bounds__(512, 4) void gemm_o(const int8_t* __restrict__ Xq,
                                                 const int8_t* __restrict__ W8,
                                                 float* __restrict__ out,
                                                 const float* __restrict__ xs,
                                                 const double* __restrict__ wsum) {
    __shared__ __align__(16) uint8_t As[2][128 * 128];
    __shared__ __align__(16) uint8_t Bs[2][128 * 128];

    const int tid  = threadIdx.x;
    const int lane = tid & 63;
    const int wv   = tid >> 6;
    const int rg   = wv >> 1, cg = wv & 1;
    const int n    = lane & 15, quad = lane >> 4;
    const int row0 = blockIdx.y * 128;
    const int col0 = blockIdx.x * 128;

    i32x4 acc[2][4] = {};

    auto stage = [&](int k0, int buf) {
#pragma unroll
        for (int ps = 0; ps < 2; ps++) {
            int p = ps * 512 + wv * 64 + lane;
            int r = p >> 3, s = p & 7;
            int c = s ^ (r & 7);
            async16(Xq + (size_t)(row0 + r) * D + k0 + c * 16,
                    &As[buf][(ps * 512 + wv * 64) * 16]);
        }
#pragma unroll
        for (int ps = 0; ps < 2; ps++) {
            int p = ps * 512 + wv * 64 + lane;
            int r = p >> 3, s = p & 7;
            int c = s ^ (r & 7);
            async16(W8 + (size_t)(col0 + r) * D + k0 + c * 16,
                    &Bs[buf][(ps * 512 + wv * 64) * 16]);
        }
    };

    stage(0, 0);
    __syncthreads();

    for (int k0 = 0; k0 < D; k0 += 128) {
        const int cur = (k0 >> 7) & 1;
        if (k0 + 128 < D) stage(k0 + 128, cur ^ 1);
#pragma unroll
        for (int t = 0; t < 2; t++) {
            i32x4 af[2], bfr[4];
#pragma unroll
            for (int mt = 0; mt < 2; mt++) {
                int r = rg * 32 + mt * 16 + n;
                af[mt] = *(const i32x4*)&As[cur][r * 128 + (((t * 4 + quad) ^ (r & 7)) * 16)];
            }
#pragma unroll
            for (int nt = 0; nt < 4; nt++) {
                int rb = cg * 64 + nt * 16 + n;
                bfr[nt] = *(const i32x4*)&Bs[cur][rb * 128 + (((t * 4 + quad) ^ (rb & 7)) * 16)];
            }
#pragma unroll
            for (int mt = 0; mt < 2; mt++)
#pragma unroll
                for (int nt = 0; nt < 4; nt++)
                    acc[mt][nt] = __builtin_amdgcn_mfma_i32_16x16x64_i8(af[mt], bfr[nt], acc[mt][nt], 0, 0, 0);
        }
        __syncthreads();
    }

    float w = fmaxf((float)(wsum[3] / (double)(D * D)), 1e-5f);
#pragma unroll
    for (int mt = 0; mt < 2; mt++) {
#pragma unroll
        for (int r2 = 0; r2 < 4; r2++) {
            int row = row0 + rg * 32 + mt * 16 + quad * 4 + r2;
            float f = w * xs[row] * (1.0f / 127.0f);
#pragma unroll
            for (int nt = 0; nt < 4; nt++)
                out[(size_t)row * D + col0 + cg * 64 + nt * 16 + n] = (float)acc[mt][nt][r2] * f;
        }
    }
}

// ---------------- MFMA flash attention: 8-wave blocks, 2 blocks/CU ----
// grid (8, H, B) = 512 blocks (grid-limited to 2/CU), 512 threads (8 waves).
// Block p handles causal strips p and 15-p; wave wv owns 2 q-tiles:
// {p,15-p}*128 + wv*16. The pairing gives every block exactly
// (2p+2)+(32-2p) = 34 tile-activations over 32-2p staged chunks: balanced
// blocks, 2 tile-computes per staged chunk.
// __launch_bounds__(512, 4): VGPR cap 128. DO NOT raise the min-waves arg --
// (512,6) caps VGPR at ~85 and this structure needs ~90: it spills to scratch
// (r5: FETCH+WRITE 440MB, 173us vs 91us). Grid is 2 blocks/CU anyway, so a
// tighter bound cannot buy occupancy, only spill.
// Register diet keeps VGPR ~60 (no kf/vf arrays, scalar l accumulation).
// Defer-max (T13, THR=8 log2-units) + s_setprio around MFMA clusters (T5).
__global__ __launch_bounds__(512, 4) void attn_mfma_kernel(const uint16_t* __restrict__ qh,
                                                           const uint16_t* __restrict__ kh,
                                                           const uint16_t* __restrict__ vt,
                                                           float* __restrict__ out) {
    __shared__ __align__(16) uint16_t KsB[2][64 * 64];
    __shared__ __align__(16) uint16_t VtB[2][64 * 64];
    __shared__ __align__(16) uint16_t Pw[8][16 * 72];   // per-wave P [q][key] (one tile)

    const int tid  = threadIdx.x;
    const int lane = tid & 63;
    const int wv   = tid >> 6;            // 0..7
    const int p = blockIdx.x, h = blockIdx.y, b = blockIdx.z;
    const int kvh = h >> 2;               // n_rep = 4
    const int n = lane & 15, quad = lane >> 4;
    const float SC = 0.125f * 1.44269504089f;   // score -> log2 units
    const float DEFER = 44.3614f;               // 8 / SC: defer-max threshold (score units)

    // 2 q-tiles per wave: one from strip p (short), one from strip 15-p (long)
    int q_lo[2] = { p * 128 + wv * 16, (15 - p) * 128 + wv * 16 };

    bf16x8 qf[2][2];
#pragma unroll
    for (int i = 0; i < 2; i++) {
        const uint16_t* qp = qh + (size_t)(b * T + q_lo[i] + n) * D + h * HD + quad * 8;
        qf[i][0] = *(const bf16x8*)(qp);
        qf[i][1] = *(const bf16x8*)(qp + 32);
    }

    f32x4 o[2][4] = {};
    float ls[2] = { 0.f, 0.f };
    float m[2] = { -INFINITY, -INFINITY };

    const uint16_t* kbase = kh + (size_t)b * T * OKV + kvh * HD;
    const uint16_t* vbase = vt + (size_t)(b * KVH + kvh) * 64 * T;

    const int nch = 32 - 2 * p;           // chunks for the longer strip (15-p)

    // stage chunk 0 -> buf 0: 512 threads x 16B = exactly one 64x64 bf16 tile each
    {
        int r = tid >> 3, sl = tid & 7;
        int c = sl ^ (r & 7);
        async16(kbase + (size_t)r * OKV + c * 8, &KsB[0][wv * 512]);
        async16(vbase + (size_t)r * T + c * 8,   &VtB[0][wv * 512]);
    }
    __syncthreads();

    for (int ch = 0; ch < nch; ch++) {
        const int cur = ch & 1;
        if (ch + 1 < nch) {   // prefetch next chunk into alternate buffer
            const int t1 = (ch + 1) * 64;
            int r = tid >> 3, sl = tid & 7;
            int c = sl ^ (r & 7);
            async16(kbase + (size_t)(t1 + r) * OKV + c * 8, &KsB[cur ^ 1][wv * 512]);
            async16(vbase + (size_t)r * T + t1 + c * 8,     &VtB[cur ^ 1][wv * 512]);
        }
        const int t0 = ch * 64;
        const uint16_t* Ks = KsB[cur];
        const uint16_t* Vs = VtB[cur];

        // fused per-tile: QK^T -> softmax -> P roundtrip -> PV^T
#pragma unroll
        for (int i = 0; i < 2; i++) {
            if (t0 > q_lo[i] + 15) continue;
            f32x4 sv[4] = {};
            __builtin_amdgcn_s_setprio(1);
#pragma unroll
            for (int ks = 0; ks < 2; ks++)
#pragma unroll
                for (int mt = 0; mt < 4; mt++) {
                    int r = mt * 16 + n;
                    bf16x8 kfr = *(const bf16x8*)&Ks[r * 64 + (((ks * 4 + quad) ^ (n & 7)) * 8)];
                    sv[mt] = __builtin_amdgcn_mfma_f32_16x16x32_bf16(kfr, qf[i][ks], sv[mt], 0, 0, 0);
                }
            __builtin_amdgcn_s_setprio(0);

            const int qg = q_lo[i] + n;
            const bool diag = (t0 + 63 > q_lo[i]);
            if (diag) {        // wave-uniform branch: mask only on diagonal chunks
#pragma unroll
                for (int mt = 0; mt < 4; mt++)
#pragma unroll
                    for (int r2 = 0; r2 < 4; r2++) {
                        int kg = t0 + mt * 16 + quad * 4 + r2;
                        if (kg > qg) sv[mt][r2] = -INFINITY;
                    }
            }
            // row-max via v_max3 tree (15 fmax -> 7 ops)
            float r0 = max3f(sv[0][0], sv[0][1], sv[0][2]);
            float r1 = max3f(sv[0][3], sv[1][0], sv[1][1]);
            float r2m = max3f(sv[1][2], sv[1][3], sv[2][0]);
            float r3 = max3f(sv[2][1], sv[2][2], sv[2][3]);
            float r4 = max3f(sv[3][0], sv[3][1], sv[3][2]);
            float mloc = fmaxf(max3f(max3f(r0, r1, r2m), r3, r4), sv[3][3]);
            mloc = fmaxf(mloc, __shfl_xor(mloc, 16));
            mloc = fmaxf(mloc, __shfl_xor(mloc, 32));
            // defer-max: only pay the rescale pass when the max moved >DEFER.
            // P values then bounded by 2^8; f32 accumulation has ample headroom.
            bool upd = (mloc > m[i] + DEFER);
            if (__ballot(upd)) {
                float mnew = fmaxf(m[i], mloc);
                float corr = fast_exp2((m[i] - mnew) * SC);   // ==1 when unchanged; 0 on first chunk
                m[i] = mnew;
#pragma unroll
                for (int mt = 0; mt < 4; mt++)
#pragma unroll
                    for (int r2 = 0; r2 < 4; r2++) o[i][mt][r2] *= corr;
                ls[i] *= corr;
            }
            float msc = m[i] * SC;
#pragma unroll
            for (int mt = 0; mt < 4; mt++) {
                float pv[4];
#pragma unroll
                for (int r2 = 0; r2 < 4; r2++)
                    pv[r2] = fast_exp2(__builtin_fmaf(sv[mt][r2], SC, -msc));
                ls[i] += (pv[0] + pv[1]) + (pv[2] + pv[3]);
                uint2 w2;
                w2.x = pack_bf16(pv[0], pv[1]);
                w2.y = pack_bf16(pv[2], pv[3]);
                *(uint2*)&Pw[wv][n * 72 + mt * 16 + quad * 4] = w2;
            }
            __builtin_amdgcn_s_setprio(1);
#pragma unroll
            for (int ks = 0; ks < 2; ks++) {
                bf16x8 pf = *(const bf16x8*)&Pw[wv][n * 72 + ks * 32 + quad * 8];
#pragma unroll
                for (int mt = 0; mt < 4; mt++) {
                    int r = mt * 16 + n;
                    bf16x8 vfr = *(const bf16x8*)&Vs[r * 64 + (((ks * 4 + quad) ^ (n & 7)) * 8)];
                    o[i][mt] = __builtin_amdgcn_mfma_f32_16x16x32_bf16(vfr, pf, o[i][mt], 0, 0, 0);
                }
            }
            __builtin_amdgcn_s_setprio(0);
        }
        __syncthreads();   // publish next buffer (prefetch had full compute to land)
    }

#pragma unroll
    for (int i = 0; i < 2; i++) {
        int qg = q_lo[i] + n;
        // l for q-row n lives split across the 4 lanes of the quad group
        float l = ls[i];
        l += __shfl_xor(l, 16);
        l += __shfl_xor(l, 32);
        float inv = 1.0f / l;
#pragma unroll
        for (int mt = 0; mt < 4; mt++) {
            f32x4 ov;
#pragma unroll
            for (int r2 = 0; r2 < 4; r2++) ov[r2] = o[i][mt][r2] * inv;
            *(f32x4*)(out + (size_t)(b * T + qg) * D + h * HD + mt * 16 + quad * 4) = ov;
        }
    }
}

// ---------------- launch ----------------
extern "C" void kernel_launch(void* const* d_in, const int* in_sizes, int n_in,
                              void* d_out, int out_size, void* d_ws, size_t ws_size,
                              hipStream_t stream) {
    const float* x   = (const float*)d_in[0];
    const float* cs  = (const float*)d_in[1];
    const float* sn  = (const float*)d_in[2];
    const float* wq  = (const float*)d_in[3];
    const float* wk  = (const float*)d_in[4];
    const float* wv  = (const float*)d_in[5];
    const float* wo  = (const float*)d_in[6];
    const float* gq  = (const float*)d_in[7];
    const float* gk  = (const float*)d_in[8];
    const float* gv  = (const float*)d_in[9];
    const float* go  = (const float*)d_in[10];
    float* out = (float*)d_out;

    uint8_t* w = (uint8_t*)d_ws;
    double* wsum  = (double*)w;
    float* xs     = (float*)(w + 256);
    size_t off = 256 + 4 * (size_t)R * 4;
    int8_t* Wq8 = (int8_t*)(w + off); off += (size_t)D * D;
    int8_t* Wk8 = (int8_t*)(w + off); off += (size_t)OKV * D;
    int8_t* Wv8 = (int8_t*)(w + off); off += (size_t)OKV * D;
    int8_t* Wo8 = (int8_t*)(w + off); off += (size_t)D * D;
    int8_t* Xq_q = (int8_t*)(w + off); off += (size_t)R * D;
    int8_t* Xq_k = (int8_t*)(w + off); off += (size_t)R * D;
    int8_t* Xq_v = (int8_t*)(w + off); off += (size_t)R * D;
    float* ab = (float*)(w + off); off += (size_t)R * D * 4;      // attention output (f32)
    float* vb = (float*)(w + off); off += (size_t)R * OKV * 4;    // 8MB: vt (4MB) + khb (4MB)
    uint16_t* qhb = (uint16_t*)(w + off); off += (size_t)R * D * 2;
    // vt and k outputs live in the vb region (both written by the fused qkv
    // gemm; must NOT alias Xq_k/Xq_v since those are concurrently read).
    // NOTE uint16 element arithmetic: khb = vtb + R*OKV elements = +4MB bytes.
    // (r6 bug: vb + R*OKV in FLOAT units = +8MB = overlapped qhb -> corruption.)
    uint16_t* vtb = (uint16_t*)vb;                  // [0, 4MB)
    uint16_t* khb = vtb + (size_t)R * OKV;          // [4MB, 8MB)
    int8_t*   Aq8 = Xq_q;              // written by rmsq AFTER q-gemm consumed Xq_q

    (void)hipMemsetAsync(wsum, 0, 64, stream);

    absmean4_kernel<<<dim3(256, 4), 256, 0, stream>>>(wq, wk, wv, wo, wsum);
    quantw4_kernel<<<dim3(1024, 4), 256, 0, stream>>>(wq, wk, wv, wo, Wq8, Wk8, Wv8, Wo8, wsum);

    rmsq3_kernel<<<R, 256, 0, stream>>>(x, gq, gk, gv, Xq_q, Xq_k, Xq_v,
                                        xs + 0 * R, xs + 1 * R, xs + 2 * R);

    // fused q+k+v projections (q: rope bf16; v: transposed bf16; k: rope bf16)
    gemm_qkv<<<dim3(24, R / 128), 512, 0, stream>>>(
        Xq_q, Xq_k, Xq_v, Wq8, Wk8, Wv8, qhb, khb, vtb, xs, wsum, cs, sn);

    attn_mfma_kernel<<<dim3(8, H, B), 512, 0, stream>>>(qhb, khb, vtb, ab);

    rmsq_kernel<<<R, 256, 0, stream>>>(ab, go, Aq8, xs + 3 * R);
    gemm_o<<<dim3(D / 128, R / 128), 512, 0, stream>>>(Aq8, Wo8, out, xs + 3 * R, wsum);
}

// Round 12
// 324.470 us; speedup vs baseline: 1.0231x; 1.0231x over previous
//
#include <hip/hip_runtime.h>
#include <stdint.h>

// Problem constants (fixed by setup_inputs)
constexpr int B   = 2;
constexpr int T   = 2048;
constexpr int D   = 2048;
constexpr int H   = 32;
constexpr int KVH = 8;
constexpr int HD  = 64;          // head dim
constexpr int R   = B * T;       // 4096 rows
constexpr int OKV = KVH * HD;    // 512

using bf16x8 = __attribute__((ext_vector_type(8))) __bf16;
using f32x4  = __attribute__((ext_vector_type(4))) float;
using i32x4  = __attribute__((ext_vector_type(4))) int;

__device__ inline float fast_exp2(float x) {
#if __has_builtin(__builtin_amdgcn_exp2f)
    return __builtin_amdgcn_exp2f(x);    // v_exp_f32: computes 2^x
#else
    return exp2f(x);
#endif
}

__device__ inline float max3f(float a, float b, float c) {
    return fmaxf(fmaxf(a, b), c);        // clang fuses to v_max3_f32 on gfx9+
}

__device__ inline uint16_t f2bf(float f) {
    uint32_t u = __float_as_uint(f);
    u += 0x7fff + ((u >> 16) & 1);   // RNE
    return (uint16_t)(u >> 16);
}

__device__ inline uint32_t pack_bf16(float a, float b) {
#if __has_builtin(__builtin_amdgcn_cvt_pk_bf16_f32)
    union { __attribute__((ext_vector_type(2))) __bf16 v; uint32_t u; } r;
    r.v = __builtin_amdgcn_cvt_pk_bf16_f32(a, b);
    return r.u;
#else
    return (uint32_t)f2bf(a) | ((uint32_t)f2bf(b) << 16);
#endif
}

// async global->LDS, 16B per lane; LDS dest = (wave-uniform) base + lane*16
__device__ inline void async16(const void* g, void* l) {
    __builtin_amdgcn_global_load_lds((const __attribute__((address_space(1))) unsigned int*)g,
                                     (__attribute__((address_space(3))) unsigned int*)l,
                                     16, 0, 0);
}

// ---------------- weight scales: mean(|w|), all 4 weights in one launch --------
__global__ void absmean4_kernel(const float* __restrict__ w0, const float* __restrict__ w1,
                                const float* __restrict__ w2, const float* __restrict__ w3,
                                double* __restrict__ sums) {
    __shared__ float red[256];
    const float* ws[4] = {w0, w1, w2, w3};
    const int ns[4] = {D * D, OKV * D, OKV * D, D * D};
    int wi = blockIdx.y;
    const float* w = ws[wi];
    int n = ns[wi];
    int tid = threadIdx.x;
    float s = 0.f;
    for (int i = blockIdx.x * 256 + tid; i < n; i += gridDim.x * 256)
        s += fabsf(w[i]);
    red[tid] = s;
    __syncthreads();
    for (int st = 128; st > 0; st >>= 1) {
        if (tid < st) red[tid] += red[tid + st];
        __syncthreads();
    }
    if (tid == 0) atomicAdd(&sums[wi], (double)red[0]);
}

// ---------------- ternary weight quantization, all 4 in one launch ----------------
__global__ void quantw4_kernel(const float* __restrict__ w0, const float* __restrict__ w1,
                               const float* __restrict__ w2, const float* __restrict__ w3,
                               int8_t* __restrict__ o0, int8_t* __restrict__ o1,
                               int8_t* __restrict__ o2, int8_t* __restrict__ o3,
                               const double* __restrict__ sums) {
    const float* ws[4] = {w0, w1, w2, w3};
    int8_t* os[4] = {o0, o1, o2, o3};
    const int ns[4] = {D * D, OKV * D, OKV * D, D * D};
    int wi = blockIdx.y;
    const float* w = ws[wi];
    int8_t* o = os[wi];
    int n = ns[wi];
    float wsc = fmaxf((float)(sums[wi] / (double)n), 1e-5f);
    for (int i = blockIdx.x * 256 + threadIdx.x; i < n; i += gridDim.x * 256) {
        float q = rintf(w[i] / wsc);
        q = fminf(fmaxf(q, -1.f), 1.f);
        o[i] = (int8_t)q;
    }
}

// ---------------- fused rmsnorm + absmax int8 quant for q,k,v ----------------
__global__ __launch_bounds__(256) void rmsq3_kernel(const float* __restrict__ X,
        const float* __restrict__ g0, const float* __restrict__ g1, const float* __restrict__ g2,
        int8_t* __restrict__ o0, int8_t* __restrict__ o1, int8_t* __restrict__ o2,
        float* __restrict__ s0, float* __restrict__ s1, float* __restrict__ s2) {
    __shared__ float red[256];
    int row = blockIdx.x, tid = threadIdx.x;
    const float* xr = X + (size_t)row * D;
    float xv[8];
    float ss = 0.f;
#pragma unroll
    for (int i = 0; i < 8; i++) { xv[i] = xr[tid + 256 * i]; ss += xv[i] * xv[i]; }
    red[tid] = ss;
    __syncthreads();
    for (int st = 128; st > 0; st >>= 1) {
        if (tid < st) red[tid] += red[tid + st];
        __syncthreads();
    }
    float rstd = 1.0f / sqrtf(red[0] / (float)D + 1e-6f);

    const float* gs[3] = {g0, g1, g2};
    int8_t* os[3] = {o0, o1, o2};
    float* sc[3] = {s0, s1, s2};
#pragma unroll
    for (int v = 0; v < 3; v++) {
        float xn[8];
        float amax = 0.f;
#pragma unroll
        for (int i = 0; i < 8; i++) {
            xn[i] = xv[i] * rstd * gs[v][tid + 256 * i];
            amax = fmaxf(amax, fabsf(xn[i]));
        }
        __syncthreads();
        red[tid] = amax;
        __syncthreads();
        for (int st = 128; st > 0; st >>= 1) {
            if (tid < st) red[tid] = fmaxf(red[tid], red[tid + st]);
            __syncthreads();
        }
        float xsv = fmaxf(red[0], 1e-5f);
        float q127 = 127.0f / xsv;
#pragma unroll
        for (int i = 0; i < 8; i++) {
            float q = rintf(xn[i] * q127);
            q = fminf(fmaxf(q, -128.f), 127.f);
            os[v][(size_t)row * D + tid + 256 * i] = (int8_t)q;
        }
        if (tid == 0) sc[v][row] = xsv;
    }
}

// ---------------- rmsnorm + quant (single, for o-proj input) ----------------
// register-cached: one global read of the row, like rmsq3
__global__ __launch_bounds__(256) void rmsq_kernel(const float* __restrict__ X,
                                                   const float* __restrict__ g,
                                                   int8_t* __restrict__ Xq,
                                                   float* __restrict__ xs_out) {
    __shared__ float red[256];
    int row = blockIdx.x, tid = threadIdx.x;
    const float* xr = X + (size_t)row * D;
    float xv[8];
    float ss = 0.f;
#pragma unroll
    for (int i = 0; i < 8; i++) { xv[i] = xr[tid + 256 * i]; ss += xv[i] * xv[i]; }
    red[tid] = ss;
    __syncthreads();
    for (int st = 128; st > 0; st >>= 1) {
        if (tid < st) red[tid] += red[tid + st];
        __syncthreads();
    }
    float rstd = 1.0f / sqrtf(red[0] / (float)D + 1e-6f);

    float xn[8];
    float amax = 0.f;
#pragma unroll
    for (int i = 0; i < 8; i++) {
        xn[i] = xv[i] * rstd * g[tid + 256 * i];
        amax = fmaxf(amax, fabsf(xn[i]));
    }
    __syncthreads();
    red[tid] = amax;
    __syncthreads();
    for (int st = 128; st > 0; st >>= 1) {
        if (tid < st) red[tid] = fmaxf(red[tid], red[tid + st]);
        __syncthreads();
    }
    float xs = fmaxf(red[0], 1e-5f);
    float q127 = 127.0f / xs;
#pragma unroll
    for (int i = 0; i < 8; i++) {
        float q = rintf(xn[i] * q127);
        q = fminf(fmaxf(q, -128.f), 127.f);
        Xq[(size_t)row * D + tid + 256 * i] = (int8_t)q;
    }
    if (tid == 0) xs_out[row] = xs;
}

// ===================== unified i8 MFMA GEMM core =====================
// r10 post-mortem: GEMMs are neither MFMA- nor LDS-throughput-bound; both
// pipes low + 2 blocks/CU => latency-bound (barrier drain with nothing
// resident to hide it). Fix: BK=64 => LDS 32 KB/block (2buf x 8KB x {A,B})
// => 3-4 blocks/CU resident (was 2): co-resident blocks interleave across
// the per-K-step barrier (m114 implicit overlap -- attn's mechanism).
// Row swizzle: chunk c = s ^ ((r + (r>>2)) & 3) -- plain r&3 would collide
// rows {0,4,8,12}; this spreads them (worst 2-way = free).
// 8 waves as 4 row-groups x 2 col-groups; wave = 32 rows x 64 cols.

// ---------------- fused q+k+v projection GEMM ----------------
// grid (24, R/128): x<16 -> q; x 16..19 -> v (transposed out); x 20..23 -> k.
__global__ __launch_bounds__(512, 4) void gemm_qkv(const int8_t* __restrict__ Xqq,
                                                   const int8_t* __restrict__ Xqk,
                                                   const int8_t* __restrict__ Xqv,
                                                   const int8_t* __restrict__ Wq8,
                                                   const int8_t* __restrict__ Wk8,
                                                   const int8_t* __restrict__ Wv8,
                                                   uint16_t* __restrict__ qout,
                                                   uint16_t* __restrict__ kout,
                                                   uint16_t* __restrict__ vt,
                                                   const float* __restrict__ xs,
                                                   const double* __restrict__ wsum,
                                                   const float* __restrict__ cs,
                                                   const float* __restrict__ sn) {
    __shared__ __align__(16) uint8_t As[2][128 * 64];
    __shared__ __align__(16) uint8_t Bs[2][128 * 64];

    const int bx = blockIdx.x;
    const int z  = (bx < 16) ? 0 : ((bx < 20) ? 1 : 2);   // 0=q 1=v 2=k
    const int xb = (bx < 16) ? bx : ((bx - 16) & 3);
    const int8_t* X  = (z == 0) ? Xqq : ((z == 1) ? Xqv : Xqk);
    const int8_t* W  = (z == 0) ? Wq8 : ((z == 1) ? Wv8 : Wk8);
    const float* xsr = (z == 0) ? xs : ((z == 1) ? xs + 2 * R : xs + R);
    const int wi = (z == 0) ? 0 : ((z == 1) ? 2 : 1);
    const double nw = (z == 0) ? (double)(D * D) : (double)(OKV * D);

    const int tid  = threadIdx.x;
    const int lane = tid & 63;
    const int wv   = tid >> 6;
    const int rg   = wv >> 1, cg = wv & 1;       // 4 row-groups x 2 col-groups
    const int n    = lane & 15, quad = lane >> 4;
    const int row0 = blockIdx.y * 128;
    const int col0 = xb * 128;

    i32x4 acc[2][4] = {};

    // stage one BK=64 slab: 512 lanes x 16B = 8KB = full 128x64 tile, 1 pass each
    auto stage = [&](int k0, int buf) {
        int r = tid >> 2, s = tid & 3;
        int c = s ^ ((r + (r >> 2)) & 3);
        async16(X + (size_t)(row0 + r) * D + k0 + c * 16, &As[buf][wv * 1024]);
        async16(W + (size_t)(col0 + r) * D + k0 + c * 16, &Bs[buf][wv * 1024]);
    };

    stage(0, 0);
    __syncthreads();

    for (int k0 = 0; k0 < D; k0 += 64) {
        const int cur = (k0 >> 6) & 1;
        if (k0 + 64 < D) stage(k0 + 64, cur ^ 1);
        i32x4 af[2];
#pragma unroll
        for (int mt = 0; mt < 2; mt++) {
            int r = rg * 32 + mt * 16 + n;
            af[mt] = *(const i32x4*)&As[cur][r * 64 + ((quad ^ ((r + (r >> 2)) & 3)) * 16)];
        }
#pragma unroll
        for (int nt = 0; nt < 4; nt++) {
            int rb = cg * 64 + nt * 16 + n;
            i32x4 bfr = *(const i32x4*)&Bs[cur][rb * 64 + ((quad ^ ((rb + (rb >> 2)) & 3)) * 16)];
            acc[0][nt] = __builtin_amdgcn_mfma_i32_16x16x64_i8(af[0], bfr, acc[0][nt], 0, 0, 0);
            acc[1][nt] = __builtin_amdgcn_mfma_i32_16x16x64_i8(af[1], bfr, acc[1][nt], 0, 0, 0);
        }
        __syncthreads();   // drains prefetch + guards buf reuse
    }

    float w = fmaxf((float)(wsum[wi] / nw), 1e-5f);
    if (z == 1) {
        // v: transposed bf16 write vt[(b*KVH+kvh)*64+d][t]
#pragma unroll
        for (int mt = 0; mt < 2; mt++) {
            int rowb = row0 + rg * 32 + mt * 16 + quad * 4;
            int bb = rowb >> 11;              // rowb / T
            int tb = rowb & (T - 1);
            float fr[4];
#pragma unroll
            for (int r2 = 0; r2 < 4; r2++)
                fr[r2] = w * xsr[rowb + r2] * (1.0f / 127.0f);
#pragma unroll
            for (int nt = 0; nt < 4; nt++) {
                int col = col0 + cg * 64 + nt * 16 + n;
                int kvh = col >> 6, d = col & 63;
                uint2 w2;
                w2.x = pack_bf16((float)acc[mt][nt][0] * fr[0], (float)acc[mt][nt][1] * fr[1]);
                w2.y = pack_bf16((float)acc[mt][nt][2] * fr[2], (float)acc[mt][nt][3] * fr[3]);
                *(uint2*)(vt + ((size_t)(bb * KVH + kvh) * 64 + d) * T + tb) = w2;
            }
        }
    } else {
        uint16_t* out = (z == 0) ? qout : kout;
        const int O   = (z == 0) ? D : OKV;
#pragma unroll
        for (int mt = 0; mt < 2; mt++) {
#pragma unroll
            for (int r2 = 0; r2 < 4; r2++) {
                int row = row0 + rg * 32 + mt * 16 + quad * 4 + r2;
                float f = w * xsr[row] * (1.0f / 127.0f);
                int t = row & (T - 1);
#pragma unroll
                for (int nt = 0; nt < 2; nt++) {      // rope pair (nt, nt+2)
                    int i = nt * 16 + n;              // within-head col < 32
                    float a  = (float)acc[mt][nt][r2] * f;
                    float bb = (float)acc[mt][nt + 2][r2] * f;
                    float c0 = cs[t * HD + i],      s0 = sn[t * HD + i];
                    float c1 = cs[t * HD + i + 32], s1 = sn[t * HD + i + 32];
                    out[(size_t)row * O + col0 + cg * 64 + i]      = f2bf(a * c0 - bb * s0);
                    out[(size_t)row * O + col0 + cg * 64 + i + 32] = f2bf(bb * c1 + a * s1);
                }
            }
        }
    }
}

// ---------------- o-projection GEMM (f32 out) ----------------
__global__ __launch_bounds__(512, 4) void gemm_o(const int8_t* __restrict__ Xq,
                                                 const int8_t* __restrict__ W8,
                                                 float* __restrict__ out,
                                                 const float* __restrict__ xs,
                                                 const double* __restrict__ wsum) {
    __shared__ __align__(16) uint8_t As[2][128 * 64];
    __shared__ __align__(16) uint8_t Bs[2][128 * 64];

    const int tid  = threadIdx.x;
    const int lane = tid & 63;
    const int wv   = tid >> 6;
    const int rg   = wv >> 1, cg = wv & 1;
    const int n    = lane & 15, quad = lane >> 4;
    const int row0 = blockIdx.y * 128;
    const int col0 = blockIdx.x * 128;

    i32x4 acc[2][4] = {};

    auto stage = [&](int k0, int buf) {
        int r = tid >> 2, s = tid & 3;
        int c = s ^ ((r + (r >> 2)) & 3);
        async16(Xq + (size_t)(row0 + r) * D + k0 + c * 16, &As[buf][wv * 1024]);
        async16(W8 + (size_t)(col0 + r) * D + k0 + c * 16, &Bs[buf][wv * 1024]);
    };

    stage(0, 0);
    __syncthreads();

    for (int k0 = 0; k0 < D; k0 += 64) {
        const int cur = (k0 >> 6) & 1;
        if (k0 + 64 < D) stage(k0 + 64, cur ^ 1);
        i32x4 af[2];
#pragma unroll
        for (int mt = 0; mt < 2; mt++) {
            int r = rg * 32 + mt * 16 + n;
            af[mt] = *(const i32x4*)&As[cur][r * 64 + ((quad ^ ((r + (r >> 2)) & 3)) * 16)];
        }
#pragma unroll
        for (int nt = 0; nt < 4; nt++) {
            int rb = cg * 64 + nt * 16 + n;
            i32x4 bfr = *(const i32x4*)&Bs[cur][rb * 64 + ((quad ^ ((rb + (rb >> 2)) & 3)) * 16)];
            acc[0][nt] = __builtin_amdgcn_mfma_i32_16x16x64_i8(af[0], bfr, acc[0][nt], 0, 0, 0);
            acc[1][nt] = __builtin_amdgcn_mfma_i32_16x16x64_i8(af[1], bfr, acc[1][nt], 0, 0, 0);
        }
        __syncthreads();
    }

    float w = fmaxf((float)(wsum[3] / (double)(D * D)), 1e-5f);
#pragma unroll
    for (int mt = 0; mt < 2; mt++) {
#pragma unroll
        for (int r2 = 0; r2 < 4; r2++) {
            int row = row0 + rg * 32 + mt * 16 + quad * 4 + r2;
            float f = w * xs[row] * (1.0f / 127.0f);
#pragma unroll
            for (int nt = 0; nt < 4; nt++)
                out[(size_t)row * D + col0 + cg * 64 + nt * 16 + n] = (float)acc[mt][nt][r2] * f;
        }
    }
}

// ---------------- MFMA flash attention: 8-wave blocks, 2 blocks/CU ----
// grid (8, H, B) = 512 blocks (grid-limited to 2/CU), 512 threads (8 waves).
// Block p handles causal strips p and 15-p; wave wv owns 2 q-tiles:
// {p,15-p}*128 + wv*16. The pairing gives every block exactly
// (2p+2)+(32-2p) = 34 tile-activations over 32-2p staged chunks: balanced
// blocks, 2 tile-computes per staged chunk.
// __launch_bounds__(512, 4): VGPR cap 128. DO NOT raise the min-waves arg --
// (512,6) caps VGPR at ~85 and this structure needs ~90: it spills to scratch
// (r5: FETCH+WRITE 440MB, 173us vs 91us). Grid is 2 blocks/CU anyway, so a
// tighter bound cannot buy occupancy, only spill.
// Register diet keeps VGPR ~60 (no kf/vf arrays, scalar l accumulation).
// Defer-max (T13, THR=8 log2-units) + s_setprio around MFMA clusters (T5).
__global__ __launch_bounds__(512, 4) void attn_mfma_kernel(const uint16_t* __restrict__ qh,
                                                           const uint16_t* __restrict__ kh,
                                                           const uint16_t* __restrict__ vt,
                                                           float* __restrict__ out) {
    __shared__ __align__(16) uint16_t KsB[2][64 * 64];
    __shared__ __align__(16) uint16_t VtB[2][64 * 64];
    __shared__ __align__(16) uint16_t Pw[8][16 * 72];   // per-wave P [q][key] (one tile)

    const int tid  = threadIdx.x;
    const int lane = tid & 63;
    const int wv   = tid >> 6;            // 0..7
    const int p = blockIdx.x, h = blockIdx.y, b = blockIdx.z;
    const int kvh = h >> 2;               // n_rep = 4
    const int n = lane & 15, quad = lane >> 4;
    const float SC = 0.125f * 1.44269504089f;   // score -> log2 units
    const float DEFER = 44.3614f;               // 8 / SC: defer-max threshold (score units)

    // 2 q-tiles per wave: one from strip p (short), one from strip 15-p (long)
    int q_lo[2] = { p * 128 + wv * 16, (15 - p) * 128 + wv * 16 };

    bf16x8 qf[2][2];
#pragma unroll
    for (int i = 0; i < 2; i++) {
        const uint16_t* qp = qh + (size_t)(b * T + q_lo[i] + n) * D + h * HD + quad * 8;
        qf[i][0] = *(const bf16x8*)(qp);
        qf[i][1] = *(const bf16x8*)(qp + 32);
    }

    f32x4 o[2][4] = {};
    float ls[2] = { 0.f, 0.f };
    float m[2] = { -INFINITY, -INFINITY };

    const uint16_t* kbase = kh + (size_t)b * T * OKV + kvh * HD;
    const uint16_t* vbase = vt + (size_t)(b * KVH + kvh) * 64 * T;

    const int nch = 32 - 2 * p;           // chunks for the longer strip (15-p)

    // stage chunk 0 -> buf 0: 512 threads x 16B = exactly one 64x64 bf16 tile each
    {
        int r = tid >> 3, sl = tid & 7;
        int c = sl ^ (r & 7);
        async16(kbase + (size_t)r * OKV + c * 8, &KsB[0][wv * 512]);
        async16(vbase + (size_t)r * T + c * 8,   &VtB[0][wv * 512]);
    }
    __syncthreads();

    for (int ch = 0; ch < nch; ch++) {
        const int cur = ch & 1;
        if (ch + 1 < nch) {   // prefetch next chunk into alternate buffer
            const int t1 = (ch + 1) * 64;
            int r = tid >> 3, sl = tid & 7;
            int c = sl ^ (r & 7);
            async16(kbase + (size_t)(t1 + r) * OKV + c * 8, &KsB[cur ^ 1][wv * 512]);
            async16(vbase + (size_t)r * T + t1 + c * 8,     &VtB[cur ^ 1][wv * 512]);
        }
        const int t0 = ch * 64;
        const uint16_t* Ks = KsB[cur];
        const uint16_t* Vs = VtB[cur];

        // fused per-tile: QK^T -> softmax -> P roundtrip -> PV^T
#pragma unroll
        for (int i = 0; i < 2; i++) {
            if (t0 > q_lo[i] + 15) continue;
            f32x4 sv[4] = {};
            __builtin_amdgcn_s_setprio(1);
#pragma unroll
            for (int ks = 0; ks < 2; ks++)
#pragma unroll
                for (int mt = 0; mt < 4; mt++) {
                    int r = mt * 16 + n;
                    bf16x8 kfr = *(const bf16x8*)&Ks[r * 64 + (((ks * 4 + quad) ^ (n & 7)) * 8)];
                    sv[mt] = __builtin_amdgcn_mfma_f32_16x16x32_bf16(kfr, qf[i][ks], sv[mt], 0, 0, 0);
                }
            __builtin_amdgcn_s_setprio(0);

            const int qg = q_lo[i] + n;
            const bool diag = (t0 + 63 > q_lo[i]);
            if (diag) {        // wave-uniform branch: mask only on diagonal chunks
#pragma unroll
                for (int mt = 0; mt < 4; mt++)
#pragma unroll
                    for (int r2 = 0; r2 < 4; r2++) {
                        int kg = t0 + mt * 16 + quad * 4 + r2;
                        if (kg > qg) sv[mt][r2] = -INFINITY;
                    }
            }
            // row-max via v_max3 tree (15 fmax -> 7 ops)
            float r0 = max3f(sv[0][0], sv[0][1], sv[0][2]);
            float r1 = max3f(sv[0][3], sv[1][0], sv[1][1]);
            float r2m = max3f(sv[1][2], sv[1][3], sv[2][0]);
            float r3 = max3f(sv[2][1], sv[2][2], sv[2][3]);
            float r4 = max3f(sv[3][0], sv[3][1], sv[3][2]);
            float mloc = fmaxf(max3f(max3f(r0, r1, r2m), r3, r4), sv[3][3]);
            mloc = fmaxf(mloc, __shfl_xor(mloc, 16));
            mloc = fmaxf(mloc, __shfl_xor(mloc, 32));
            // defer-max: only pay the rescale pass when the max moved >DEFER.
            // P values then bounded by 2^8; f32 accumulation has ample headroom.
            bool upd = (mloc > m[i] + DEFER);
            if (__ballot(upd)) {
                float mnew = fmaxf(m[i], mloc);
                float corr = fast_exp2((m[i] - mnew) * SC);   // ==1 when unchanged; 0 on first chunk
                m[i] = mnew;
#pragma unroll
                for (int mt = 0; mt < 4; mt++)
#pragma unroll
                    for (int r2 = 0; r2 < 4; r2++) o[i][mt][r2] *= corr;
                ls[i] *= corr;
            }
            float msc = m[i] * SC;
#pragma unroll
            for (int mt = 0; mt < 4; mt++) {
                float pv[4];
#pragma unroll
                for (int r2 = 0; r2 < 4; r2++)
                    pv[r2] = fast_exp2(__builtin_fmaf(sv[mt][r2], SC, -msc));
                ls[i] += (pv[0] + pv[1]) + (pv[2] + pv[3]);
                uint2 w2;
                w2.x = pack_bf16(pv[0], pv[1]);
                w2.y = pack_bf16(pv[2], pv[3]);
                *(uint2*)&Pw[wv][n * 72 + mt * 16 + quad * 4] = w2;
            }
            __builtin_amdgcn_s_setprio(1);
#pragma unroll
            for (int ks = 0; ks < 2; ks++) {
                bf16x8 pf = *(const bf16x8*)&Pw[wv][n * 72 + ks * 32 + quad * 8];
#pragma unroll
                for (int mt = 0; mt < 4; mt++) {
                    int r = mt * 16 + n;
                    bf16x8 vfr = *(const bf16x8*)&Vs[r * 64 + (((ks * 4 + quad) ^ (n & 7)) * 8)];
                    o[i][mt] = __builtin_amdgcn_mfma_f32_16x16x32_bf16(vfr, pf, o[i][mt], 0, 0, 0);
                }
            }
            __builtin_amdgcn_s_setprio(0);
        }
        __syncthreads();   // publish next buffer (prefetch had full compute to land)
    }

#pragma unroll
    for (int i = 0; i < 2; i++) {
        int qg = q_lo[i] + n;
        // l for q-row n lives split across the 4 lanes of the quad group
        float l = ls[i];
        l += __shfl_xor(l, 16);
        l += __shfl_xor(l, 32);
        float inv = 1.0f / l;
#pragma unroll
        for (int mt = 0; mt < 4; mt++) {
            f32x4 ov;
#pragma unroll
            for (int r2 = 0; r2 < 4; r2++) ov[r2] = o[i][mt][r2] * inv;
            *(f32x4*)(out + (size_t)(b * T + qg) * D + h * HD + mt * 16 + quad * 4) = ov;
        }
    }
}

// ---------------- launch ----------------
extern "C" void kernel_launch(void* const* d_in, const int* in_sizes, int n_in,
                              void* d_out, int out_size, void* d_ws, size_t ws_size,
                              hipStream_t stream) {
    const float* x   = (const float*)d_in[0];
    const float* cs  = (const float*)d_in[1];
    const float* sn  = (const float*)d_in[2];
    const float* wq  = (const float*)d_in[3];
    const float* wk  = (const float*)d_in[4];
    const float* wv  = (const float*)d_in[5];
    const float* wo  = (const float*)d_in[6];
    const float* gq  = (const float*)d_in[7];
    const float* gk  = (const float*)d_in[8];
    const float* gv  = (const float*)d_in[9];
    const float* go  = (const float*)d_in[10];
    float* out = (float*)d_out;

    uint8_t* w = (uint8_t*)d_ws;
    double* wsum  = (double*)w;
    float* xs     = (float*)(w + 256);
    size_t off = 256 + 4 * (size_t)R * 4;
    int8_t* Wq8 = (int8_t*)(w + off); off += (size_t)D * D;
    int8_t* Wk8 = (int8_t*)(w + off); off += (size_t)OKV * D;
    int8_t* Wv8 = (int8_t*)(w + off); off += (size_t)OKV * D;
    int8_t* Wo8 = (int8_t*)(w + off); off += (size_t)D * D;
    int8_t* Xq_q = (int8_t*)(w + off); off += (size_t)R * D;
    int8_t* Xq_k = (int8_t*)(w + off); off += (size_t)R * D;
    int8_t* Xq_v = (int8_t*)(w + off); off += (size_t)R * D;
    float* ab = (float*)(w + off); off += (size_t)R * D * 4;      // attention output (f32)
    float* vb = (float*)(w + off); off += (size_t)R * OKV * 4;    // 8MB: vt (4MB) + khb (4MB)
    uint16_t* qhb = (uint16_t*)(w + off); off += (size_t)R * D * 2;
    // vt and k outputs live in the vb region (both written by the fused qkv
    // gemm; must NOT alias Xq_k/Xq_v since those are concurrently read).
    // NOTE uint16 element arithmetic: khb = vtb + R*OKV elements = +4MB bytes.
    // (r6 bug: vb + R*OKV in FLOAT units = +8MB = overlapped qhb -> corruption.)
    uint16_t* vtb = (uint16_t*)vb;                  // [0, 4MB)
    uint16_t* khb = vtb + (size_t)R * OKV;          // [4MB, 8MB)
    int8_t*   Aq8 = Xq_q;              // written by rmsq AFTER q-gemm consumed Xq_q

    (void)hipMemsetAsync(wsum, 0, 64, stream);

    absmean4_kernel<<<dim3(256, 4), 256, 0, stream>>>(wq, wk, wv, wo, wsum);
    quantw4_kernel<<<dim3(1024, 4), 256, 0, stream>>>(wq, wk, wv, wo, Wq8, Wk8, Wv8, Wo8, wsum);

    rmsq3_kernel<<<R, 256, 0, stream>>>(x, gq, gk, gv, Xq_q, Xq_k, Xq_v,
                                        xs + 0 * R, xs + 1 * R, xs + 2 * R);

    // fused q+k+v projections (q: rope bf16; v: transposed bf16; k: rope bf16)
    gemm_qkv<<<dim3(24, R / 128), 512, 0, stream>>>(
        Xq_q, Xq_k, Xq_v, Wq8, Wk8, Wv8, qhb, khb, vtb, xs, wsum, cs, sn);

    attn_mfma_kernel<<<dim3(8, H, B), 512, 0, stream>>>(qhb, khb, vtb, ab);

    rmsq_kernel<<<R, 256, 0, stream>>>(ab, go, Aq8, xs + 3 * R);
    gemm_o<<<dim3(D / 128, R / 128), 512, 0, stream>>>(Aq8, Wo8, out, xs + 3 * R, wsum);
}

// Round 13
// 321.193 us; speedup vs baseline: 1.0335x; 1.0102x over previous
//
#include <hip/hip_runtime.h>
#include <stdint.h>

// Problem constants (fixed by setup_inputs)
constexpr int B   = 2;
constexpr int T   = 2048;
constexpr int D   = 2048;
constexpr int H   = 32;
constexpr int KVH = 8;
constexpr int HD  = 64;          // head dim
constexpr int R   = B * T;       // 4096 rows
constexpr int OKV = KVH * HD;    // 512

using bf16x8 = __attribute__((ext_vector_type(8))) __bf16;
using f32x4  = __attribute__((ext_vector_type(4))) float;
using i32x4  = __attribute__((ext_vector_type(4))) int;

__device__ inline float fast_exp2(float x) {
#if __has_builtin(__builtin_amdgcn_exp2f)
    return __builtin_amdgcn_exp2f(x);    // v_exp_f32: computes 2^x
#else
    return exp2f(x);
#endif
}

__device__ inline float max3f(float a, float b, float c) {
    return fmaxf(fmaxf(a, b), c);        // clang fuses to v_max3_f32 on gfx9+
}

__device__ inline uint16_t f2bf(float f) {
    uint32_t u = __float_as_uint(f);
    u += 0x7fff + ((u >> 16) & 1);   // RNE
    return (uint16_t)(u >> 16);
}

__device__ inline float bf2f(uint16_t v) {
    return __uint_as_float((uint32_t)v << 16);
}

__device__ inline uint32_t pack_bf16(float a, float b) {
#if __has_builtin(__builtin_amdgcn_cvt_pk_bf16_f32)
    union { __attribute__((ext_vector_type(2))) __bf16 v; uint32_t u; } r;
    r.v = __builtin_amdgcn_cvt_pk_bf16_f32(a, b);
    return r.u;
#else
    return (uint32_t)f2bf(a) | ((uint32_t)f2bf(b) << 16);
#endif
}

// async global->LDS, 16B per lane; LDS dest = (wave-uniform) base + lane*16
__device__ inline void async16(const void* g, void* l) {
    __builtin_amdgcn_global_load_lds((const __attribute__((address_space(1))) unsigned int*)g,
                                     (__attribute__((address_space(3))) unsigned int*)l,
                                     16, 0, 0);
}

// ---------------- merged prep: rmsnorm+quant (q,k,v) PARALLEL-TO weight absmean --
// blocks [0, R): rmsq3 for row=bx. blocks [R, R+1024): absmean for weight
// (bx-R)>>8, x-block (bx-R)&255. The two halves are data-independent; merging
// hides the shorter under the longer and removes one serialized launch gap.
__global__ __launch_bounds__(256) void prep_kernel(const float* __restrict__ X,
        const float* __restrict__ g0, const float* __restrict__ g1, const float* __restrict__ g2,
        int8_t* __restrict__ o0, int8_t* __restrict__ o1, int8_t* __restrict__ o2,
        float* __restrict__ s0, float* __restrict__ s1, float* __restrict__ s2,
        const float* __restrict__ w0, const float* __restrict__ w1,
        const float* __restrict__ w2, const float* __restrict__ w3,
        double* __restrict__ sums) {
    __shared__ float red[256];
    const int bx = blockIdx.x, tid = threadIdx.x;

    if (bx >= R) {
        // ---- absmean over one weight's strided slice ----
        const float* ws[4] = {w0, w1, w2, w3};
        const int ns[4] = {D * D, OKV * D, OKV * D, D * D};
        int bx2 = bx - R;
        int wi = bx2 >> 8, xb = bx2 & 255;
        const float* w = ws[wi];
        int n = ns[wi];
        float s = 0.f;
        for (int i = xb * 256 + tid; i < n; i += 256 * 256)
            s += fabsf(w[i]);
        red[tid] = s;
        __syncthreads();
        for (int st = 128; st > 0; st >>= 1) {
            if (tid < st) red[tid] += red[tid + st];
            __syncthreads();
        }
        if (tid == 0) atomicAdd(&sums[wi], (double)red[0]);
        return;
    }

    // ---- rmsq3 for row = bx ----
    int row = bx;
    const float* xr = X + (size_t)row * D;
    float xv[8];
    float ss = 0.f;
#pragma unroll
    for (int i = 0; i < 8; i++) { xv[i] = xr[tid + 256 * i]; ss += xv[i] * xv[i]; }
    red[tid] = ss;
    __syncthreads();
    for (int st = 128; st > 0; st >>= 1) {
        if (tid < st) red[tid] += red[tid + st];
        __syncthreads();
    }
    float rstd = 1.0f / sqrtf(red[0] / (float)D + 1e-6f);

    const float* gs[3] = {g0, g1, g2};
    int8_t* os[3] = {o0, o1, o2};
    float* sc[3] = {s0, s1, s2};
#pragma unroll
    for (int v = 0; v < 3; v++) {
        float xn[8];
        float amax = 0.f;
#pragma unroll
        for (int i = 0; i < 8; i++) {
            xn[i] = xv[i] * rstd * gs[v][tid + 256 * i];
            amax = fmaxf(amax, fabsf(xn[i]));
        }
        __syncthreads();
        red[tid] = amax;
        __syncthreads();
        for (int st = 128; st > 0; st >>= 1) {
            if (tid < st) red[tid] = fmaxf(red[tid], red[tid + st]);
            __syncthreads();
        }
        float xsv = fmaxf(red[0], 1e-5f);
        float q127 = 127.0f / xsv;
#pragma unroll
        for (int i = 0; i < 8; i++) {
            float q = rintf(xn[i] * q127);
            q = fminf(fmaxf(q, -128.f), 127.f);
            os[v][(size_t)row * D + tid + 256 * i] = (int8_t)q;
        }
        if (tid == 0) sc[v][row] = xsv;
    }
}

// ---------------- ternary weight quantization, all 4 in one launch ----------------
__global__ void quantw4_kernel(const float* __restrict__ w0, const float* __restrict__ w1,
                               const float* __restrict__ w2, const float* __restrict__ w3,
                               int8_t* __restrict__ o0, int8_t* __restrict__ o1,
                               int8_t* __restrict__ o2, int8_t* __restrict__ o3,
                               const double* __restrict__ sums) {
    const float* ws[4] = {w0, w1, w2, w3};
    int8_t* os[4] = {o0, o1, o2, o3};
    const int ns[4] = {D * D, OKV * D, OKV * D, D * D};
    int wi = blockIdx.y;
    const float* w = ws[wi];
    int8_t* o = os[wi];
    int n = ns[wi];
    float wsc = fmaxf((float)(sums[wi] / (double)n), 1e-5f);
    for (int i = blockIdx.x * 256 + threadIdx.x; i < n; i += gridDim.x * 256) {
        float q = rintf(w[i] / wsc);
        q = fminf(fmaxf(q, -1.f), 1.f);
        o[i] = (int8_t)q;
    }
}

// ---------------- rmsnorm + quant of bf16 attn output (o-proj input) ----------
// vectorized: 8 bf16 elems/lane in one uint4 load; 8-byte packed int8 store.
__global__ __launch_bounds__(256) void rmsq_kernel(const uint16_t* __restrict__ X,
                                                   const float* __restrict__ g,
                                                   int8_t* __restrict__ Xq,
                                                   float* __restrict__ xs_out) {
    __shared__ float red[256];
    int row = blockIdx.x, tid = threadIdx.x;
    const uint16_t* xr = X + (size_t)row * D;
    union { uint4 u; uint16_t s[8]; } ld;
    ld.u = *(const uint4*)(xr + tid * 8);
    float xv[8];
    float ss = 0.f;
#pragma unroll
    for (int i = 0; i < 8; i++) { xv[i] = bf2f(ld.s[i]); ss += xv[i] * xv[i]; }
    red[tid] = ss;
    __syncthreads();
    for (int st = 128; st > 0; st >>= 1) {
        if (tid < st) red[tid] += red[tid + st];
        __syncthreads();
    }
    float rstd = 1.0f / sqrtf(red[0] / (float)D + 1e-6f);

    float xn[8];
    float amax = 0.f;
#pragma unroll
    for (int i = 0; i < 8; i++) {
        xn[i] = xv[i] * rstd * g[tid * 8 + i];
        amax = fmaxf(amax, fabsf(xn[i]));
    }
    __syncthreads();
    red[tid] = amax;
    __syncthreads();
    for (int st = 128; st > 0; st >>= 1) {
        if (tid < st) red[tid] = fmaxf(red[tid], red[tid + st]);
        __syncthreads();
    }
    float xs = fmaxf(red[0], 1e-5f);
    float q127 = 127.0f / xs;
    union { uint2 u; int8_t b[8]; } st8;
#pragma unroll
    for (int i = 0; i < 8; i++) {
        float q = rintf(xn[i] * q127);
        q = fminf(fmaxf(q, -128.f), 127.f);
        st8.b[i] = (int8_t)q;
    }
    *(uint2*)(Xq + (size_t)row * D + tid * 8) = st8.u;
    if (tid == 0) xs_out[row] = xs;
}

// ===================== unified i8 MFMA GEMM core =====================
// BK=64 => LDS 32 KB/block => 3-4 blocks/CU resident; co-resident blocks
// interleave across the per-K-step barrier. Row swizzle c = s ^ ((r+(r>>2))&3).
// 8 waves as 4 row-groups x 2 col-groups; wave = 32 rows x 64 cols.

// ---------------- fused q+k+v projection GEMM ----------------
// grid (24, R/128): x<16 -> q; x 16..19 -> v (transposed out); x 20..23 -> k.
__global__ __launch_bounds__(512, 4) void gemm_qkv(const int8_t* __restrict__ Xqq,
                                                   const int8_t* __restrict__ Xqk,
                                                   const int8_t* __restrict__ Xqv,
                                                   const int8_t* __restrict__ Wq8,
                                                   const int8_t* __restrict__ Wk8,
                                                   const int8_t* __restrict__ Wv8,
                                                   uint16_t* __restrict__ qout,
                                                   uint16_t* __restrict__ kout,
                                                   uint16_t* __restrict__ vt,
                                                   const float* __restrict__ xs,
                                                   const double* __restrict__ wsum,
                                                   const float* __restrict__ cs,
                                                   const float* __restrict__ sn) {
    __shared__ __align__(16) uint8_t As[2][128 * 64];
    __shared__ __align__(16) uint8_t Bs[2][128 * 64];

    const int bx = blockIdx.x;
    const int z  = (bx < 16) ? 0 : ((bx < 20) ? 1 : 2);   // 0=q 1=v 2=k
    const int xb = (bx < 16) ? bx : ((bx - 16) & 3);
    const int8_t* X  = (z == 0) ? Xqq : ((z == 1) ? Xqv : Xqk);
    const int8_t* W  = (z == 0) ? Wq8 : ((z == 1) ? Wv8 : Wk8);
    const float* xsr = (z == 0) ? xs : ((z == 1) ? xs + 2 * R : xs + R);
    const int wi = (z == 0) ? 0 : ((z == 1) ? 2 : 1);
    const double nw = (z == 0) ? (double)(D * D) : (double)(OKV * D);

    const int tid  = threadIdx.x;
    const int lane = tid & 63;
    const int wv   = tid >> 6;
    const int rg   = wv >> 1, cg = wv & 1;       // 4 row-groups x 2 col-groups
    const int n    = lane & 15, quad = lane >> 4;
    const int row0 = blockIdx.y * 128;
    const int col0 = xb * 128;

    i32x4 acc[2][4] = {};

    // stage one BK=64 slab: 512 lanes x 16B = 8KB = full 128x64 tile, 1 pass each
    auto stage = [&](int k0, int buf) {
        int r = tid >> 2, s = tid & 3;
        int c = s ^ ((r + (r >> 2)) & 3);
        async16(X + (size_t)(row0 + r) * D + k0 + c * 16, &As[buf][wv * 1024]);
        async16(W + (size_t)(col0 + r) * D + k0 + c * 16, &Bs[buf][wv * 1024]);
    };

    stage(0, 0);
    __syncthreads();

    for (int k0 = 0; k0 < D; k0 += 64) {
        const int cur = (k0 >> 6) & 1;
        if (k0 + 64 < D) stage(k0 + 64, cur ^ 1);
        i32x4 af[2];
#pragma unroll
        for (int mt = 0; mt < 2; mt++) {
            int r = rg * 32 + mt * 16 + n;
            af[mt] = *(const i32x4*)&As[cur][r * 64 + ((quad ^ ((r + (r >> 2)) & 3)) * 16)];
        }
#pragma unroll
        for (int nt = 0; nt < 4; nt++) {
            int rb = cg * 64 + nt * 16 + n;
            i32x4 bfr = *(const i32x4*)&Bs[cur][rb * 64 + ((quad ^ ((rb + (rb >> 2)) & 3)) * 16)];
            acc[0][nt] = __builtin_amdgcn_mfma_i32_16x16x64_i8(af[0], bfr, acc[0][nt], 0, 0, 0);
            acc[1][nt] = __builtin_amdgcn_mfma_i32_16x16x64_i8(af[1], bfr, acc[1][nt], 0, 0, 0);
        }
        __syncthreads();   // drains prefetch + guards buf reuse
    }

    float w = fmaxf((float)(wsum[wi] / nw), 1e-5f);
    if (z == 1) {
        // v: transposed bf16 write vt[(b*KVH+kvh)*64+d][t]
#pragma unroll
        for (int mt = 0; mt < 2; mt++) {
            int rowb = row0 + rg * 32 + mt * 16 + quad * 4;
            int bb = rowb >> 11;              // rowb / T
            int tb = rowb & (T - 1);
            float fr[4];
#pragma unroll
            for (int r2 = 0; r2 < 4; r2++)
                fr[r2] = w * xsr[rowb + r2] * (1.0f / 127.0f);
#pragma unroll
            for (int nt = 0; nt < 4; nt++) {
                int col = col0 + cg * 64 + nt * 16 + n;
                int kvh = col >> 6, d = col & 63;
                uint2 w2;
                w2.x = pack_bf16((float)acc[mt][nt][0] * fr[0], (float)acc[mt][nt][1] * fr[1]);
                w2.y = pack_bf16((float)acc[mt][nt][2] * fr[2], (float)acc[mt][nt][3] * fr[3]);
                *(uint2*)(vt + ((size_t)(bb * KVH + kvh) * 64 + d) * T + tb) = w2;
            }
        }
    } else {
        uint16_t* out = (z == 0) ? qout : kout;
        const int O   = (z == 0) ? D : OKV;
#pragma unroll
        for (int mt = 0; mt < 2; mt++) {
#pragma unroll
            for (int r2 = 0; r2 < 4; r2++) {
                int row = row0 + rg * 32 + mt * 16 + quad * 4 + r2;
                float f = w * xsr[row] * (1.0f / 127.0f);
                int t = row & (T - 1);
#pragma unroll
                for (int nt = 0; nt < 2; nt++) {      // rope pair (nt, nt+2)
                    int i = nt * 16 + n;              // within-head col < 32
                    float a  = (float)acc[mt][nt][r2] * f;
                    float bb = (float)acc[mt][nt + 2][r2] * f;
                    float c0 = cs[t * HD + i],      s0 = sn[t * HD + i];
                    float c1 = cs[t * HD + i + 32], s1 = sn[t * HD + i + 32];
                    out[(size_t)row * O + col0 + cg * 64 + i]      = f2bf(a * c0 - bb * s0);
                    out[(size_t)row * O + col0 + cg * 64 + i + 32] = f2bf(bb * c1 + a * s1);
                }
            }
        }
    }
}

// ---------------- o-projection GEMM (f32 out) ----------------
__global__ __launch_bounds__(512, 4) void gemm_o(const int8_t* __restrict__ Xq,
                                                 const int8_t* __restrict__ W8,
                                                 float* __restrict__ out,
                                                 const float* __restrict__ xs,
                                                 const double* __restrict__ wsum) {
    __shared__ __align__(16) uint8_t As[2][128 * 64];
    __shared__ __align__(16) uint8_t Bs[2][128 * 64];

    const int tid  = threadIdx.x;
    const int lane = tid & 63;
    const int wv   = tid >> 6;
    const int rg   = wv >> 1, cg = wv & 1;
    const int n    = lane & 15, quad = lane >> 4;
    const int row0 = blockIdx.y * 128;
    const int col0 = blockIdx.x * 128;

    i32x4 acc[2][4] = {};

    auto stage = [&](int k0, int buf) {
        int r = tid >> 2, s = tid & 3;
        int c = s ^ ((r + (r >> 2)) & 3);
        async16(Xq + (size_t)(row0 + r) * D + k0 + c * 16, &As[buf][wv * 1024]);
        async16(W8 + (size_t)(col0 + r) * D + k0 + c * 16, &Bs[buf][wv * 1024]);
    };

    stage(0, 0);
    __syncthreads();

    for (int k0 = 0; k0 < D; k0 += 64) {
        const int cur = (k0 >> 6) & 1;
        if (k0 + 64 < D) stage(k0 + 64, cur ^ 1);
        i32x4 af[2];
#pragma unroll
        for (int mt = 0; mt < 2; mt++) {
            int r = rg * 32 + mt * 16 + n;
            af[mt] = *(const i32x4*)&As[cur][r * 64 + ((quad ^ ((r + (r >> 2)) & 3)) * 16)];
        }
#pragma unroll
        for (int nt = 0; nt < 4; nt++) {
            int rb = cg * 64 + nt * 16 + n;
            i32x4 bfr = *(const i32x4*)&Bs[cur][rb * 64 + ((quad ^ ((rb + (rb >> 2)) & 3)) * 16)];
            acc[0][nt] = __builtin_amdgcn_mfma_i32_16x16x64_i8(af[0], bfr, acc[0][nt], 0, 0, 0);
            acc[1][nt] = __builtin_amdgcn_mfma_i32_16x16x64_i8(af[1], bfr, acc[1][nt], 0, 0, 0);
        }
        __syncthreads();
    }

    float w = fmaxf((float)(wsum[3] / (double)(D * D)), 1e-5f);
#pragma unroll
    for (int mt = 0; mt < 2; mt++) {
#pragma unroll
        for (int r2 = 0; r2 < 4; r2++) {
            int row = row0 + rg * 32 + mt * 16 + quad * 4 + r2;
            float f = w * xs[row] * (1.0f / 127.0f);
#pragma unroll
            for (int nt = 0; nt < 4; nt++)
                out[(size_t)row * D + col0 + cg * 64 + nt * 16 + n] = (float)acc[mt][nt][r2] * f;
        }
    }
}

// ---------------- MFMA flash attention: 8-wave blocks, 2 blocks/CU ----
// grid (8, H, B) = 512 blocks (grid-limited to 2/CU), 512 threads (8 waves).
// Block p handles causal strips p and 15-p; wave wv owns 2 q-tiles:
// {p,15-p}*128 + wv*16: (2p+2)+(32-2p) = 34 tile-activations per block.
// __launch_bounds__(512, 4): VGPR cap 128. DO NOT raise (r5 spill lesson).
// Output is bf16 (halves ab roundtrip traffic; rmsq consumes bf16).
// Defer-max (T13) + s_setprio (T5) + max3 tree + uniform-branch masking.
__global__ __launch_bounds__(512, 4) void attn_mfma_kernel(const uint16_t* __restrict__ qh,
                                                           const uint16_t* __restrict__ kh,
                                                           const uint16_t* __restrict__ vt,
                                                           uint16_t* __restrict__ out) {
    __shared__ __align__(16) uint16_t KsB[2][64 * 64];
    __shared__ __align__(16) uint16_t VtB[2][64 * 64];
    __shared__ __align__(16) uint16_t Pw[8][16 * 72];   // per-wave P [q][key] (one tile)

    const int tid  = threadIdx.x;
    const int lane = tid & 63;
    const int wv   = tid >> 6;            // 0..7
    const int p = blockIdx.x, h = blockIdx.y, b = blockIdx.z;
    const int kvh = h >> 2;               // n_rep = 4
    const int n = lane & 15, quad = lane >> 4;
    const float SC = 0.125f * 1.44269504089f;   // score -> log2 units
    const float DEFER = 44.3614f;               // 8 / SC: defer-max threshold (score units)

    // 2 q-tiles per wave: one from strip p (short), one from strip 15-p (long)
    int q_lo[2] = { p * 128 + wv * 16, (15 - p) * 128 + wv * 16 };

    bf16x8 qf[2][2];
#pragma unroll
    for (int i = 0; i < 2; i++) {
        const uint16_t* qp = qh + (size_t)(b * T + q_lo[i] + n) * D + h * HD + quad * 8;
        qf[i][0] = *(const bf16x8*)(qp);
        qf[i][1] = *(const bf16x8*)(qp + 32);
    }

    f32x4 o[2][4] = {};
    float ls[2] = { 0.f, 0.f };
    float m[2] = { -INFINITY, -INFINITY };

    const uint16_t* kbase = kh + (size_t)b * T * OKV + kvh * HD;
    const uint16_t* vbase = vt + (size_t)(b * KVH + kvh) * 64 * T;

    const int nch = 32 - 2 * p;           // chunks for the longer strip (15-p)

    // stage chunk 0 -> buf 0: 512 threads x 16B = exactly one 64x64 bf16 tile each
    {
        int r = tid >> 3, sl = tid & 7;
        int c = sl ^ (r & 7);
        async16(kbase + (size_t)r * OKV + c * 8, &KsB[0][wv * 512]);
        async16(vbase + (size_t)r * T + c * 8,   &VtB[0][wv * 512]);
    }
    __syncthreads();

    for (int ch = 0; ch < nch; ch++) {
        const int cur = ch & 1;
        if (ch + 1 < nch) {   // prefetch next chunk into alternate buffer
            const int t1 = (ch + 1) * 64;
            int r = tid >> 3, sl = tid & 7;
            int c = sl ^ (r & 7);
            async16(kbase + (size_t)(t1 + r) * OKV + c * 8, &KsB[cur ^ 1][wv * 512]);
            async16(vbase + (size_t)r * T + t1 + c * 8,     &VtB[cur ^ 1][wv * 512]);
        }
        const int t0 = ch * 64;
        const uint16_t* Ks = KsB[cur];
        const uint16_t* Vs = VtB[cur];

        // fused per-tile: QK^T -> softmax -> P roundtrip -> PV^T
#pragma unroll
        for (int i = 0; i < 2; i++) {
            if (t0 > q_lo[i] + 15) continue;
            f32x4 sv[4] = {};
            __builtin_amdgcn_s_setprio(1);
#pragma unroll
            for (int ks = 0; ks < 2; ks++)
#pragma unroll
                for (int mt = 0; mt < 4; mt++) {
                    int r = mt * 16 + n;
                    bf16x8 kfr = *(const bf16x8*)&Ks[r * 64 + (((ks * 4 + quad) ^ (n & 7)) * 8)];
                    sv[mt] = __builtin_amdgcn_mfma_f32_16x16x32_bf16(kfr, qf[i][ks], sv[mt], 0, 0, 0);
                }
            __builtin_amdgcn_s_setprio(0);

            const int qg = q_lo[i] + n;
            const bool diag = (t0 + 63 > q_lo[i]);
            if (diag) {        // wave-uniform branch: mask only on diagonal chunks
#pragma unroll
                for (int mt = 0; mt < 4; mt++)
#pragma unroll
                    for (int r2 = 0; r2 < 4; r2++) {
                        int kg = t0 + mt * 16 + quad * 4 + r2;
                        if (kg > qg) sv[mt][r2] = -INFINITY;
                    }
            }
            // row-max via v_max3 tree (15 fmax -> 7 ops)
            float r0 = max3f(sv[0][0], sv[0][1], sv[0][2]);
            float r1 = max3f(sv[0][3], sv[1][0], sv[1][1]);
            float r2m = max3f(sv[1][2], sv[1][3], sv[2][0]);
            float r3 = max3f(sv[2][1], sv[2][2], sv[2][3]);
            float r4 = max3f(sv[3][0], sv[3][1], sv[3][2]);
            float mloc = fmaxf(max3f(max3f(r0, r1, r2m), r3, r4), sv[3][3]);
            mloc = fmaxf(mloc, __shfl_xor(mloc, 16));
            mloc = fmaxf(mloc, __shfl_xor(mloc, 32));
            // defer-max: only pay the rescale pass when the max moved >DEFER.
            // P values then bounded by 2^8; f32 accumulation has ample headroom.
            bool upd = (mloc > m[i] + DEFER);
            if (__ballot(upd)) {
                float mnew = fmaxf(m[i], mloc);
                float corr = fast_exp2((m[i] - mnew) * SC);   // ==1 when unchanged; 0 on first chunk
                m[i] = mnew;
#pragma unroll
                for (int mt = 0; mt < 4; mt++)
#pragma unroll
                    for (int r2 = 0; r2 < 4; r2++) o[i][mt][r2] *= corr;
                ls[i] *= corr;
            }
            float msc = m[i] * SC;
#pragma unroll
            for (int mt = 0; mt < 4; mt++) {
                float pv[4];
#pragma unroll
                for (int r2 = 0; r2 < 4; r2++)
                    pv[r2] = fast_exp2(__builtin_fmaf(sv[mt][r2], SC, -msc));
                ls[i] += (pv[0] + pv[1]) + (pv[2] + pv[3]);
                uint2 w2;
                w2.x = pack_bf16(pv[0], pv[1]);
                w2.y = pack_bf16(pv[2], pv[3]);
                *(uint2*)&Pw[wv][n * 72 + mt * 16 + quad * 4] = w2;
            }
            __builtin_amdgcn_s_setprio(1);
#pragma unroll
            for (int ks = 0; ks < 2; ks++) {
                bf16x8 pf = *(const bf16x8*)&Pw[wv][n * 72 + ks * 32 + quad * 8];
#pragma unroll
                for (int mt = 0; mt < 4; mt++) {
                    int r = mt * 16 + n;
                    bf16x8 vfr = *(const bf16x8*)&Vs[r * 64 + (((ks * 4 + quad) ^ (n & 7)) * 8)];
                    o[i][mt] = __builtin_amdgcn_mfma_f32_16x16x32_bf16(vfr, pf, o[i][mt], 0, 0, 0);
                }
            }
            __builtin_amdgcn_s_setprio(0);
        }
        __syncthreads();   // publish next buffer (prefetch had full compute to land)
    }

#pragma unroll
    for (int i = 0; i < 2; i++) {
        int qg = q_lo[i] + n;
        // l for q-row n lives split across the 4 lanes of the quad group
        float l = ls[i];
        l += __shfl_xor(l, 16);
        l += __shfl_xor(l, 32);
        float inv = 1.0f / l;
#pragma unroll
        for (int mt = 0; mt < 4; mt++) {
            uint2 w2;
            w2.x = pack_bf16(o[i][mt][0] * inv, o[i][mt][1] * inv);
            w2.y = pack_bf16(o[i][mt][2] * inv, o[i][mt][3] * inv);
            *(uint2*)(out + (size_t)(b * T + qg) * D + h * HD + mt * 16 + quad * 4) = w2;
        }
    }
}

// ---------------- launch ----------------
extern "C" void kernel_launch(void* const* d_in, const int* in_sizes, int n_in,
                              void* d_out, int out_size, void* d_ws, size_t ws_size,
                              hipStream_t stream) {
    const float* x   = (const float*)d_in[0];
    const float* cs  = (const float*)d_in[1];
    const float* sn  = (const float*)d_in[2];
    const float* wq  = (const float*)d_in[3];
    const float* wk  = (const float*)d_in[4];
    const float* wv  = (const float*)d_in[5];
    const float* wo  = (const float*)d_in[6];
    const float* gq  = (const float*)d_in[7];
    const float* gk  = (const float*)d_in[8];
    const float* gv  = (const float*)d_in[9];
    const float* go  = (const float*)d_in[10];
    float* out = (float*)d_out;

    uint8_t* w = (uint8_t*)d_ws;
    double* wsum  = (double*)w;
    float* xs     = (float*)(w + 256);
    size_t off = 256 + 4 * (size_t)R * 4;
    int8_t* Wq8 = (int8_t*)(w + off); off += (size_t)D * D;
    int8_t* Wk8 = (int8_t*)(w + off); off += (size_t)OKV * D;
    int8_t* Wv8 = (int8_t*)(w + off); off += (size_t)OKV * D;
    int8_t* Wo8 = (int8_t*)(w + off); off += (size_t)D * D;
    int8_t* Xq_q = (int8_t*)(w + off); off += (size_t)R * D;
    int8_t* Xq_k = (int8_t*)(w + off); off += (size_t)R * D;
    int8_t* Xq_v = (int8_t*)(w + off); off += (size_t)R * D;
    float* ab = (float*)(w + off); off += (size_t)R * D * 4;      // attn out (bf16, 8MB region)
    float* vb = (float*)(w + off); off += (size_t)R * OKV * 4;    // 8MB: vt (4MB) + khb (4MB)
    uint16_t* qhb = (uint16_t*)(w + off); off += (size_t)R * D * 2;
    // vt and k outputs live in the vb region (both written by the fused qkv
    // gemm; must NOT alias Xq_k/Xq_v since those are concurrently read).
    // NOTE uint16 element arithmetic: khb = vtb + R*OKV elements = +4MB bytes.
    // (r6 bug: vb + R*OKV in FLOAT units = +8MB = overlapped qhb -> corruption.)
    uint16_t* vtb = (uint16_t*)vb;                  // [0, 4MB)
    uint16_t* khb = vtb + (size_t)R * OKV;          // [4MB, 8MB)
    uint16_t* abb = (uint16_t*)ab;     // attn output as bf16 (R*D*2 = 16MB of region)
    int8_t*   Aq8 = Xq_q;              // written by rmsq AFTER q-gemm consumed Xq_q

    (void)hipMemsetAsync(wsum, 0, 64, stream);

    // rmsq3 (activations) || absmean (weights) -- independent, one launch
    prep_kernel<<<R + 1024, 256, 0, stream>>>(x, gq, gk, gv, Xq_q, Xq_k, Xq_v,
                                              xs + 0 * R, xs + 1 * R, xs + 2 * R,
                                              wq, wk, wv, wo, wsum);
    quantw4_kernel<<<dim3(1024, 4), 256, 0, stream>>>(wq, wk, wv, wo, Wq8, Wk8, Wv8, Wo8, wsum);

    // fused q+k+v projections (q: rope bf16; v: transposed bf16; k: rope bf16)
    gemm_qkv<<<dim3(24, R / 128), 512, 0, stream>>>(
        Xq_q, Xq_k, Xq_v, Wq8, Wk8, Wv8, qhb, khb, vtb, xs, wsum, cs, sn);

    attn_mfma_kernel<<<dim3(8, H, B), 512, 0, stream>>>(qhb, khb, vtb, abb);

    rmsq_kernel<<<R, 256, 0, stream>>>(abb, go, Aq8, xs + 3 * R);
    gemm_o<<<dim3(D / 128, R / 128), 512, 0, stream>>>(Aq8, Wo8, out, xs + 3 * R, wsum);
}

// Round 14
// 317.954 us; speedup vs baseline: 1.0440x; 1.0102x over previous
//
#include <hip/hip_runtime.h>
#include <stdint.h>

// Problem constants (fixed by setup_inputs)
constexpr int B   = 2;
constexpr int T   = 2048;
constexpr int D   = 2048;
constexpr int H   = 32;
constexpr int KVH = 8;
constexpr int HD  = 64;          // head dim
constexpr int R   = B * T;       // 4096 rows
constexpr int OKV = KVH * HD;    // 512

using bf16x8 = __attribute__((ext_vector_type(8))) __bf16;
using f32x4  = __attribute__((ext_vector_type(4))) float;
using i32x4  = __attribute__((ext_vector_type(4))) int;

__device__ inline float fast_exp2(float x) {
#if __has_builtin(__builtin_amdgcn_exp2f)
    return __builtin_amdgcn_exp2f(x);    // v_exp_f32: computes 2^x
#else
    return exp2f(x);
#endif
}

__device__ inline float max3f(float a, float b, float c) {
    return fmaxf(fmaxf(a, b), c);        // clang fuses to v_max3_f32 on gfx9+
}

__device__ inline uint16_t f2bf(float f) {
    uint32_t u = __float_as_uint(f);
    u += 0x7fff + ((u >> 16) & 1);   // RNE
    return (uint16_t)(u >> 16);
}

__device__ inline float bf2f(uint16_t v) {
    return __uint_as_float((uint32_t)v << 16);
}

__device__ inline uint32_t pack_bf16(float a, float b) {
#if __has_builtin(__builtin_amdgcn_cvt_pk_bf16_f32)
    union { __attribute__((ext_vector_type(2))) __bf16 v; uint32_t u; } r;
    r.v = __builtin_amdgcn_cvt_pk_bf16_f32(a, b);
    return r.u;
#else
    return (uint32_t)f2bf(a) | ((uint32_t)f2bf(b) << 16);
#endif
}

// async global->LDS, 16B per lane; LDS dest = (wave-uniform) base + lane*16
__device__ inline void async16(const void* g, void* l) {
    __builtin_amdgcn_global_load_lds((const __attribute__((address_space(1))) unsigned int*)g,
                                     (__attribute__((address_space(3))) unsigned int*)l,
                                     16, 0, 0);
}

// ---------------- merged prep: rmsnorm+quant (q,k,v) PARALLEL-TO weight absmean --
__global__ __launch_bounds__(256) void prep_kernel(const float* __restrict__ X,
        const float* __restrict__ g0, const float* __restrict__ g1, const float* __restrict__ g2,
        int8_t* __restrict__ o0, int8_t* __restrict__ o1, int8_t* __restrict__ o2,
        float* __restrict__ s0, float* __restrict__ s1, float* __restrict__ s2,
        const float* __restrict__ w0, const float* __restrict__ w1,
        const float* __restrict__ w2, const float* __restrict__ w3,
        double* __restrict__ sums) {
    __shared__ float red[256];
    const int bx = blockIdx.x, tid = threadIdx.x;

    if (bx >= R) {
        // ---- absmean over one weight's strided slice ----
        const float* ws[4] = {w0, w1, w2, w3};
        const int ns[4] = {D * D, OKV * D, OKV * D, D * D};
        int bx2 = bx - R;
        int wi = bx2 >> 8, xb = bx2 & 255;
        const float* w = ws[wi];
        int n = ns[wi];
        float s = 0.f;
        for (int i = xb * 256 + tid; i < n; i += 256 * 256)
            s += fabsf(w[i]);
        red[tid] = s;
        __syncthreads();
        for (int st = 128; st > 0; st >>= 1) {
            if (tid < st) red[tid] += red[tid + st];
            __syncthreads();
        }
        if (tid == 0) atomicAdd(&sums[wi], (double)red[0]);
        return;
    }

    // ---- rmsq3 for row = bx ----
    int row = bx;
    const float* xr = X + (size_t)row * D;
    float xv[8];
    float ss = 0.f;
#pragma unroll
    for (int i = 0; i < 8; i++) { xv[i] = xr[tid + 256 * i]; ss += xv[i] * xv[i]; }
    red[tid] = ss;
    __syncthreads();
    for (int st = 128; st > 0; st >>= 1) {
        if (tid < st) red[tid] += red[tid + st];
        __syncthreads();
    }
    float rstd = 1.0f / sqrtf(red[0] / (float)D + 1e-6f);

    const float* gs[3] = {g0, g1, g2};
    int8_t* os[3] = {o0, o1, o2};
    float* sc[3] = {s0, s1, s2};
#pragma unroll
    for (int v = 0; v < 3; v++) {
        float xn[8];
        float amax = 0.f;
#pragma unroll
        for (int i = 0; i < 8; i++) {
            xn[i] = xv[i] * rstd * gs[v][tid + 256 * i];
            amax = fmaxf(amax, fabsf(xn[i]));
        }
        __syncthreads();
        red[tid] = amax;
        __syncthreads();
        for (int st = 128; st > 0; st >>= 1) {
            if (tid < st) red[tid] = fmaxf(red[tid], red[tid + st]);
            __syncthreads();
        }
        float xsv = fmaxf(red[0], 1e-5f);
        float q127 = 127.0f / xsv;
#pragma unroll
        for (int i = 0; i < 8; i++) {
            float q = rintf(xn[i] * q127);
            q = fminf(fmaxf(q, -128.f), 127.f);
            os[v][(size_t)row * D + tid + 256 * i] = (int8_t)q;
        }
        if (tid == 0) sc[v][row] = xsv;
    }
}

// ---------------- ternary weight quantization, all 4 in one launch ----------------
__global__ void quantw4_kernel(const float* __restrict__ w0, const float* __restrict__ w1,
                               const float* __restrict__ w2, const float* __restrict__ w3,
                               int8_t* __restrict__ o0, int8_t* __restrict__ o1,
                               int8_t* __restrict__ o2, int8_t* __restrict__ o3,
                               const double* __restrict__ sums) {
    const float* ws[4] = {w0, w1, w2, w3};
    int8_t* os[4] = {o0, o1, o2, o3};
    const int ns[4] = {D * D, OKV * D, OKV * D, D * D};
    int wi = blockIdx.y;
    const float* w = ws[wi];
    int8_t* o = os[wi];
    int n = ns[wi];
    float wsc = fmaxf((float)(sums[wi] / (double)n), 1e-5f);
    for (int i = blockIdx.x * 256 + threadIdx.x; i < n; i += gridDim.x * 256) {
        float q = rintf(w[i] / wsc);
        q = fminf(fmaxf(q, -1.f), 1.f);
        o[i] = (int8_t)q;
    }
}

// ---------------- rmsnorm + quant of bf16 attn output (o-proj input) ----------
__global__ __launch_bounds__(256) void rmsq_kernel(const uint16_t* __restrict__ X,
                                                   const float* __restrict__ g,
                                                   int8_t* __restrict__ Xq,
                                                   float* __restrict__ xs_out) {
    __shared__ float red[256];
    int row = blockIdx.x, tid = threadIdx.x;
    const uint16_t* xr = X + (size_t)row * D;
    union { uint4 u; uint16_t s[8]; } ld;
    ld.u = *(const uint4*)(xr + tid * 8);
    float xv[8];
    float ss = 0.f;
#pragma unroll
    for (int i = 0; i < 8; i++) { xv[i] = bf2f(ld.s[i]); ss += xv[i] * xv[i]; }
    red[tid] = ss;
    __syncthreads();
    for (int st = 128; st > 0; st >>= 1) {
        if (tid < st) red[tid] += red[tid + st];
        __syncthreads();
    }
    float rstd = 1.0f / sqrtf(red[0] / (float)D + 1e-6f);

    float xn[8];
    float amax = 0.f;
#pragma unroll
    for (int i = 0; i < 8; i++) {
        xn[i] = xv[i] * rstd * g[tid * 8 + i];
        amax = fmaxf(amax, fabsf(xn[i]));
    }
    __syncthreads();
    red[tid] = amax;
    __syncthreads();
    for (int st = 128; st > 0; st >>= 1) {
        if (tid < st) red[tid] = fmaxf(red[tid], red[tid + st]);
        __syncthreads();
    }
    float xs = fmaxf(red[0], 1e-5f);
    float q127 = 127.0f / xs;
    union { uint2 u; int8_t b[8]; } st8;
#pragma unroll
    for (int i = 0; i < 8; i++) {
        float q = rintf(xn[i] * q127);
        q = fminf(fmaxf(q, -128.f), 127.f);
        st8.b[i] = (int8_t)q;
    }
    *(uint2*)(Xq + (size_t)row * D + tid * 8) = st8.u;
    if (tid == 0) xs_out[row] = xs;
}

// ===================== unified i8 MFMA GEMM core =====================
// BK=64, 8 waves as 4x2 groups, wave = 32 rows x 64 cols, dbuf staging.
// r13: XCD-aware panel-major block swizzle (T1). Default round-robin puts
// blocks sharing a W-panel on DIFFERENT XCDs -> every panel re-read misses
// the per-XCD L2 and goes to L3 (invisible in FETCH_SIZE). Bijective swizzle
// swz=(lin%8)*cpx+lin/8 (nwg%8==0) + panel-major decode gives each XCD a few
// consecutive W-panels x all row-blocks: panel re-reads become L2 hits.

// ---------------- fused q+k+v projection GEMM ----------------
// 768 blocks; panel-major decode: xbz = swz/32 (0..15 q, 16..19 v, 20..23 k),
// row-block = swz%32. Each XCD owns 96 blocks = 3 panels x 32 rows.
__global__ __launch_bounds__(512, 4) void gemm_qkv(const int8_t* __restrict__ Xqq,
                                                   const int8_t* __restrict__ Xqk,
                                                   const int8_t* __restrict__ Xqv,
                                                   const int8_t* __restrict__ Wq8,
                                                   const int8_t* __restrict__ Wk8,
                                                   const int8_t* __restrict__ Wv8,
                                                   uint16_t* __restrict__ qout,
                                                   uint16_t* __restrict__ kout,
                                                   uint16_t* __restrict__ vt,
                                                   const float* __restrict__ xs,
                                                   const double* __restrict__ wsum,
                                                   const float* __restrict__ cs,
                                                   const float* __restrict__ sn) {
    __shared__ __align__(16) uint8_t As[2][128 * 64];
    __shared__ __align__(16) uint8_t Bs[2][128 * 64];

    const int lin = blockIdx.y * 24 + blockIdx.x;         // 0..767
    const int swz = (lin & 7) * 96 + (lin >> 3);          // XCD-chunked, bijective
    const int xbz = swz >> 5;                             // panel 0..23
    const int rowb = swz & 31;                            // row-block 0..31

    const int z  = (xbz < 16) ? 0 : ((xbz < 20) ? 1 : 2);   // 0=q 1=v 2=k
    const int xb = (xbz < 16) ? xbz : ((xbz - 16) & 3);
    const int8_t* X  = (z == 0) ? Xqq : ((z == 1) ? Xqv : Xqk);
    const int8_t* W  = (z == 0) ? Wq8 : ((z == 1) ? Wv8 : Wk8);
    const float* xsr = (z == 0) ? xs : ((z == 1) ? xs + 2 * R : xs + R);
    const int wi = (z == 0) ? 0 : ((z == 1) ? 2 : 1);
    const double nw = (z == 0) ? (double)(D * D) : (double)(OKV * D);

    const int tid  = threadIdx.x;
    const int lane = tid & 63;
    const int wv   = tid >> 6;
    const int rg   = wv >> 1, cg = wv & 1;       // 4 row-groups x 2 col-groups
    const int n    = lane & 15, quad = lane >> 4;
    const int row0 = rowb * 128;
    const int col0 = xb * 128;

    i32x4 acc[2][4] = {};

    // stage one BK=64 slab: 512 lanes x 16B = 8KB = full 128x64 tile, 1 pass each
    auto stage = [&](int k0, int buf) {
        int r = tid >> 2, s = tid & 3;
        int c = s ^ ((r + (r >> 2)) & 3);
        async16(X + (size_t)(row0 + r) * D + k0 + c * 16, &As[buf][wv * 1024]);
        async16(W + (size_t)(col0 + r) * D + k0 + c * 16, &Bs[buf][wv * 1024]);
    };

    stage(0, 0);
    __syncthreads();

    for (int k0 = 0; k0 < D; k0 += 64) {
        const int cur = (k0 >> 6) & 1;
        if (k0 + 64 < D) stage(k0 + 64, cur ^ 1);
        i32x4 af[2];
#pragma unroll
        for (int mt = 0; mt < 2; mt++) {
            int r = rg * 32 + mt * 16 + n;
            af[mt] = *(const i32x4*)&As[cur][r * 64 + ((quad ^ ((r + (r >> 2)) & 3)) * 16)];
        }
#pragma unroll
        for (int nt = 0; nt < 4; nt++) {
            int rb = cg * 64 + nt * 16 + n;
            i32x4 bfr = *(const i32x4*)&Bs[cur][rb * 64 + ((quad ^ ((rb + (rb >> 2)) & 3)) * 16)];
            acc[0][nt] = __builtin_amdgcn_mfma_i32_16x16x64_i8(af[0], bfr, acc[0][nt], 0, 0, 0);
            acc[1][nt] = __builtin_amdgcn_mfma_i32_16x16x64_i8(af[1], bfr, acc[1][nt], 0, 0, 0);
        }
        __syncthreads();   // drains prefetch + guards buf reuse
    }

    float w = fmaxf((float)(wsum[wi] / nw), 1e-5f);
    if (z == 1) {
        // v: transposed bf16 write vt[(b*KVH+kvh)*64+d][t]
#pragma unroll
        for (int mt = 0; mt < 2; mt++) {
            int rwb = row0 + rg * 32 + mt * 16 + quad * 4;
            int bb = rwb >> 11;              // rwb / T
            int tb = rwb & (T - 1);
            float fr[4];
#pragma unroll
            for (int r2 = 0; r2 < 4; r2++)
                fr[r2] = w * xsr[rwb + r2] * (1.0f / 127.0f);
#pragma unroll
            for (int nt = 0; nt < 4; nt++) {
                int col = col0 + cg * 64 + nt * 16 + n;
                int kvh = col >> 6, d = col & 63;
                uint2 w2;
                w2.x = pack_bf16((float)acc[mt][nt][0] * fr[0], (float)acc[mt][nt][1] * fr[1]);
                w2.y = pack_bf16((float)acc[mt][nt][2] * fr[2], (float)acc[mt][nt][3] * fr[3]);
                *(uint2*)(vt + ((size_t)(bb * KVH + kvh) * 64 + d) * T + tb) = w2;
            }
        }
    } else {
        uint16_t* out = (z == 0) ? qout : kout;
        const int O   = (z == 0) ? D : OKV;
#pragma unroll
        for (int mt = 0; mt < 2; mt++) {
#pragma unroll
            for (int r2 = 0; r2 < 4; r2++) {
                int row = row0 + rg * 32 + mt * 16 + quad * 4 + r2;
                float f = w * xsr[row] * (1.0f / 127.0f);
                int t = row & (T - 1);
#pragma unroll
                for (int nt = 0; nt < 2; nt++) {      // rope pair (nt, nt+2)
                    int i = nt * 16 + n;              // within-head col < 32
                    float a  = (float)acc[mt][nt][r2] * f;
                    float bb = (float)acc[mt][nt + 2][r2] * f;
                    float c0 = cs[t * HD + i],      s0 = sn[t * HD + i];
                    float c1 = cs[t * HD + i + 32], s1 = sn[t * HD + i + 32];
                    out[(size_t)row * O + col0 + cg * 64 + i]      = f2bf(a * c0 - bb * s0);
                    out[(size_t)row * O + col0 + cg * 64 + i + 32] = f2bf(bb * c1 + a * s1);
                }
            }
        }
    }
}

// ---------------- o-projection GEMM (f32 out) ----------------
// 512 blocks; panel-major decode: each XCD owns 64 blocks = 2 panels x 32 rows.
__global__ __launch_bounds__(512, 4) void gemm_o(const int8_t* __restrict__ Xq,
                                                 const int8_t* __restrict__ W8,
                                                 float* __restrict__ out,
                                                 const float* __restrict__ xs,
                                                 const double* __restrict__ wsum) {
    __shared__ __align__(16) uint8_t As[2][128 * 64];
    __shared__ __align__(16) uint8_t Bs[2][128 * 64];

    const int lin = blockIdx.y * 16 + blockIdx.x;         // 0..511
    const int swz = (lin & 7) * 64 + (lin >> 3);          // XCD-chunked, bijective
    const int colp = swz >> 5;                            // panel 0..15
    const int rowb = swz & 31;                            // row-block 0..31

    const int tid  = threadIdx.x;
    const int lane = tid & 63;
    const int wv   = tid >> 6;
    const int rg   = wv >> 1, cg = wv & 1;
    const int n    = lane & 15, quad = lane >> 4;
    const int row0 = rowb * 128;
    const int col0 = colp * 128;

    i32x4 acc[2][4] = {};

    auto stage = [&](int k0, int buf) {
        int r = tid >> 2, s = tid & 3;
        int c = s ^ ((r + (r >> 2)) & 3);
        async16(Xq + (size_t)(row0 + r) * D + k0 + c * 16, &As[buf][wv * 1024]);
        async16(W8 + (size_t)(col0 + r) * D + k0 + c * 16, &Bs[buf][wv * 1024]);
    };

    stage(0, 0);
    __syncthreads();

    for (int k0 = 0; k0 < D; k0 += 64) {
        const int cur = (k0 >> 6) & 1;
        if (k0 + 64 < D) stage(k0 + 64, cur ^ 1);
        i32x4 af[2];
#pragma unroll
        for (int mt = 0; mt < 2; mt++) {
            int r = rg * 32 + mt * 16 + n;
            af[mt] = *(const i32x4*)&As[cur][r * 64 + ((quad ^ ((r + (r >> 2)) & 3)) * 16)];
        }
#pragma unroll
        for (int nt = 0; nt < 4; nt++) {
            int rb = cg * 64 + nt * 16 + n;
            i32x4 bfr = *(const i32x4*)&Bs[cur][rb * 64 + ((quad ^ ((rb + (rb >> 2)) & 3)) * 16)];
            acc[0][nt] = __builtin_amdgcn_mfma_i32_16x16x64_i8(af[0], bfr, acc[0][nt], 0, 0, 0);
            acc[1][nt] = __builtin_amdgcn_mfma_i32_16x16x64_i8(af[1], bfr, acc[1][nt], 0, 0, 0);
        }
        __syncthreads();
    }

    float w = fmaxf((float)(wsum[3] / (double)(D * D)), 1e-5f);
#pragma unroll
    for (int mt = 0; mt < 2; mt++) {
#pragma unroll
        for (int r2 = 0; r2 < 4; r2++) {
            int row = row0 + rg * 32 + mt * 16 + quad * 4 + r2;
            float f = w * xs[row] * (1.0f / 127.0f);
#pragma unroll
            for (int nt = 0; nt < 4; nt++)
                out[(size_t)row * D + col0 + cg * 64 + nt * 16 + n] = (float)acc[mt][nt][r2] * f;
        }
    }
}

// ---------------- MFMA flash attention: 8-wave blocks, 2 blocks/CU ----
// grid (8, H, B) = 512 blocks, 512 threads. Block p handles strips p and 15-p;
// wave wv owns 2 q-tiles. (512,4): DO NOT raise min-waves (r5 spill lesson).
// bf16 output. Defer-max (T13) + s_setprio (T5) + max3 tree + uniform masking.
__global__ __launch_bounds__(512, 4) void attn_mfma_kernel(const uint16_t* __restrict__ qh,
                                                           const uint16_t* __restrict__ kh,
                                                           const uint16_t* __restrict__ vt,
                                                           uint16_t* __restrict__ out) {
    __shared__ __align__(16) uint16_t KsB[2][64 * 64];
    __shared__ __align__(16) uint16_t VtB[2][64 * 64];
    __shared__ __align__(16) uint16_t Pw[8][16 * 72];   // per-wave P [q][key] (one tile)

    const int tid  = threadIdx.x;
    const int lane = tid & 63;
    const int wv   = tid >> 6;            // 0..7
    const int p = blockIdx.x, h = blockIdx.y, b = blockIdx.z;
    const int kvh = h >> 2;               // n_rep = 4
    const int n = lane & 15, quad = lane >> 4;
    const float SC = 0.125f * 1.44269504089f;   // score -> log2 units
    const float DEFER = 44.3614f;               // 8 / SC: defer-max threshold (score units)

    // 2 q-tiles per wave: one from strip p (short), one from strip 15-p (long)
    int q_lo[2] = { p * 128 + wv * 16, (15 - p) * 128 + wv * 16 };

    bf16x8 qf[2][2];
#pragma unroll
    for (int i = 0; i < 2; i++) {
        const uint16_t* qp = qh + (size_t)(b * T + q_lo[i] + n) * D + h * HD + quad * 8;
        qf[i][0] = *(const bf16x8*)(qp);
        qf[i][1] = *(const bf16x8*)(qp + 32);
    }

    f32x4 o[2][4] = {};
    float ls[2] = { 0.f, 0.f };
    float m[2] = { -INFINITY, -INFINITY };

    const uint16_t* kbase = kh + (size_t)b * T * OKV + kvh * HD;
    const uint16_t* vbase = vt + (size_t)(b * KVH + kvh) * 64 * T;

    const int nch = 32 - 2 * p;           // chunks for the longer strip (15-p)

    // stage chunk 0 -> buf 0: 512 threads x 16B = exactly one 64x64 bf16 tile each
    {
        int r = tid >> 3, sl = tid & 7;
        int c = sl ^ (r & 7);
        async16(kbase + (size_t)r * OKV + c * 8, &KsB[0][wv * 512]);
        async16(vbase + (size_t)r * T + c * 8,   &VtB[0][wv * 512]);
    }
    __syncthreads();

    for (int ch = 0; ch < nch; ch++) {
        const int cur = ch & 1;
        if (ch + 1 < nch) {   // prefetch next chunk into alternate buffer
            const int t1 = (ch + 1) * 64;
            int r = tid >> 3, sl = tid & 7;
            int c = sl ^ (r & 7);
            async16(kbase + (size_t)(t1 + r) * OKV + c * 8, &KsB[cur ^ 1][wv * 512]);
            async16(vbase + (size_t)r * T + t1 + c * 8,     &VtB[cur ^ 1][wv * 512]);
        }
        const int t0 = ch * 64;
        const uint16_t* Ks = KsB[cur];
        const uint16_t* Vs = VtB[cur];

        // fused per-tile: QK^T -> softmax -> P roundtrip -> PV^T
#pragma unroll
        for (int i = 0; i < 2; i++) {
            if (t0 > q_lo[i] + 15) continue;
            f32x4 sv[4] = {};
            __builtin_amdgcn_s_setprio(1);
#pragma unroll
            for (int ks = 0; ks < 2; ks++)
#pragma unroll
                for (int mt = 0; mt < 4; mt++) {
                    int r = mt * 16 + n;
                    bf16x8 kfr = *(const bf16x8*)&Ks[r * 64 + (((ks * 4 + quad) ^ (n & 7)) * 8)];
                    sv[mt] = __builtin_amdgcn_mfma_f32_16x16x32_bf16(kfr, qf[i][ks], sv[mt], 0, 0, 0);
                }
            __builtin_amdgcn_s_setprio(0);

            const int qg = q_lo[i] + n;
            const bool diag = (t0 + 63 > q_lo[i]);
            if (diag) {        // wave-uniform branch: mask only on diagonal chunks
#pragma unroll
                for (int mt = 0; mt < 4; mt++)
#pragma unroll
                    for (int r2 = 0; r2 < 4; r2++) {
                        int kg = t0 + mt * 16 + quad * 4 + r2;
                        if (kg > qg) sv[mt][r2] = -INFINITY;
                    }
            }
            // row-max via v_max3 tree (15 fmax -> 7 ops)
            float r0 = max3f(sv[0][0], sv[0][1], sv[0][2]);
            float r1 = max3f(sv[0][3], sv[1][0], sv[1][1]);
            float r2m = max3f(sv[1][2], sv[1][3], sv[2][0]);
            float r3 = max3f(sv[2][1], sv[2][2], sv[2][3]);
            float r4 = max3f(sv[3][0], sv[3][1], sv[3][2]);
            float mloc = fmaxf(max3f(max3f(r0, r1, r2m), r3, r4), sv[3][3]);
            mloc = fmaxf(mloc, __shfl_xor(mloc, 16));
            mloc = fmaxf(mloc, __shfl_xor(mloc, 32));
            // defer-max: only pay the rescale pass when the max moved >DEFER.
            // P values then bounded by 2^8; f32 accumulation has ample headroom.
            bool upd = (mloc > m[i] + DEFER);
            if (__ballot(upd)) {
                float mnew = fmaxf(m[i], mloc);
                float corr = fast_exp2((m[i] - mnew) * SC);   // ==1 when unchanged; 0 on first chunk
                m[i] = mnew;
#pragma unroll
                for (int mt = 0; mt < 4; mt++)
#pragma unroll
                    for (int r2 = 0; r2 < 4; r2++) o[i][mt][r2] *= corr;
                ls[i] *= corr;
            }
            float msc = m[i] * SC;
#pragma unroll
            for (int mt = 0; mt < 4; mt++) {
                float pv[4];
#pragma unroll
                for (int r2 = 0; r2 < 4; r2++)
                    pv[r2] = fast_exp2(__builtin_fmaf(sv[mt][r2], SC, -msc));
                ls[i] += (pv[0] + pv[1]) + (pv[2] + pv[3]);
                uint2 w2;
                w2.x = pack_bf16(pv[0], pv[1]);
                w2.y = pack_bf16(pv[2], pv[3]);
                *(uint2*)&Pw[wv][n * 72 + mt * 16 + quad * 4] = w2;
            }
            __builtin_amdgcn_s_setprio(1);
#pragma unroll
            for (int ks = 0; ks < 2; ks++) {
                bf16x8 pf = *(const bf16x8*)&Pw[wv][n * 72 + ks * 32 + quad * 8];
#pragma unroll
                for (int mt = 0; mt < 4; mt++) {
                    int r = mt * 16 + n;
                    bf16x8 vfr = *(const bf16x8*)&Vs[r * 64 + (((ks * 4 + quad) ^ (n & 7)) * 8)];
                    o[i][mt] = __builtin_amdgcn_mfma_f32_16x16x32_bf16(vfr, pf, o[i][mt], 0, 0, 0);
                }
            }
            __builtin_amdgcn_s_setprio(0);
        }
        __syncthreads();   // publish next buffer (prefetch had full compute to land)
    }

#pragma unroll
    for (int i = 0; i < 2; i++) {
        int qg = q_lo[i] + n;
        // l for q-row n lives split across the 4 lanes of the quad group
        float l = ls[i];
        l += __shfl_xor(l, 16);
        l += __shfl_xor(l, 32);
        float inv = 1.0f / l;
#pragma unroll
        for (int mt = 0; mt < 4; mt++) {
            uint2 w2;
            w2.x = pack_bf16(o[i][mt][0] * inv, o[i][mt][1] * inv);
            w2.y = pack_bf16(o[i][mt][2] * inv, o[i][mt][3] * inv);
            *(uint2*)(out + (size_t)(b * T + qg) * D + h * HD + mt * 16 + quad * 4) = w2;
        }
    }
}

// ---------------- launch ----------------
extern "C" void kernel_launch(void* const* d_in, const int* in_sizes, int n_in,
                              void* d_out, int out_size, void* d_ws, size_t ws_size,
                              hipStream_t stream) {
    const float* x   = (const float*)d_in[0];
    const float* cs  = (const float*)d_in[1];
    const float* sn  = (const float*)d_in[2];
    const float* wq  = (const float*)d_in[3];
    const float* wk  = (const float*)d_in[4];
    const float* wv  = (const float*)d_in[5];
    const float* wo  = (const float*)d_in[6];
    const float* gq  = (const float*)d_in[7];
    const float* gk  = (const float*)d_in[8];
    const float* gv  = (const float*)d_in[9];
    const float* go  = (const float*)d_in[10];
    float* out = (float*)d_out;

    uint8_t* w = (uint8_t*)d_ws;
    double* wsum  = (double*)w;
    float* xs     = (float*)(w + 256);
    size_t off = 256 + 4 * (size_t)R * 4;
    int8_t* Wq8 = (int8_t*)(w + off); off += (size_t)D * D;
    int8_t* Wk8 = (int8_t*)(w + off); off += (size_t)OKV * D;
    int8_t* Wv8 = (int8_t*)(w + off); off += (size_t)OKV * D;
    int8_t* Wo8 = (int8_t*)(w + off); off += (size_t)D * D;
    int8_t* Xq_q = (int8_t*)(w + off); off += (size_t)R * D;
    int8_t* Xq_k = (int8_t*)(w + off); off += (size_t)R * D;
    int8_t* Xq_v = (int8_t*)(w + off); off += (size_t)R * D;
    float* ab = (float*)(w + off); off += (size_t)R * D * 4;      // attn out (bf16, 8MB region)
    float* vb = (float*)(w + off); off += (size_t)R * OKV * 4;    // 8MB: vt (4MB) + khb (4MB)
    uint16_t* qhb = (uint16_t*)(w + off); off += (size_t)R * D * 2;
    // vt and k outputs live in the vb region (both written by the fused qkv
    // gemm; must NOT alias Xq_k/Xq_v since those are concurrently read).
    // NOTE uint16 element arithmetic: khb = vtb + R*OKV elements = +4MB bytes.
    // (r6 bug: vb + R*OKV in FLOAT units = +8MB = overlapped qhb -> corruption.)
    uint16_t* vtb = (uint16_t*)vb;                  // [0, 4MB)
    uint16_t* khb = vtb + (size_t)R * OKV;          // [4MB, 8MB)
    uint16_t* abb = (uint16_t*)ab;     // attn output as bf16 (R*D*2 = 16MB of region)
    int8_t*   Aq8 = Xq_q;              // written by rmsq AFTER q-gemm consumed Xq_q

    (void)hipMemsetAsync(wsum, 0, 64, stream);

    // rmsq3 (activations) || absmean (weights) -- independent, one launch
    prep_kernel<<<R + 1024, 256, 0, stream>>>(x, gq, gk, gv, Xq_q, Xq_k, Xq_v,
                                              xs + 0 * R, xs + 1 * R, xs + 2 * R,
                                              wq, wk, wv, wo, wsum);
    quantw4_kernel<<<dim3(1024, 4), 256, 0, stream>>>(wq, wk, wv, wo, Wq8, Wk8, Wv8, Wo8, wsum);

    // fused q+k+v projections (q: rope bf16; v: transposed bf16; k: rope bf16)
    gemm_qkv<<<dim3(24, R / 128), 512, 0, stream>>>(
        Xq_q, Xq_k, Xq_v, Wq8, Wk8, Wv8, qhb, khb, vtb, xs, wsum, cs, sn);

    attn_mfma_kernel<<<dim3(8, H, B), 512, 0, stream>>>(qhb, khb, vtb, abb);

    rmsq_kernel<<<R, 256, 0, stream>>>(abb, go, Aq8, xs + 3 * R);
    gemm_o<<<dim3(D / 128, R / 128), 512, 0, stream>>>(Aq8, Wo8, out, xs + 3 * R, wsum);
}